// Round 17
// baseline (1019.797 us; speedup 1.0000x reference)
//
#include <hip/hip_runtime.h>
#include <math.h>

typedef short bf16x8 __attribute__((ext_vector_type(8)));
typedef float f32x4 __attribute__((ext_vector_type(4)));

__device__ __forceinline__ float sigf(float x) {
    return __builtin_amdgcn_rcpf(1.f + __expf(-x));
}
__device__ __forceinline__ float tanhf_fast(float x) {
    const float e = __expf(2.f * x);
    return 1.f - 2.f * __builtin_amdgcn_rcpf(e + 1.f);
}

__device__ __forceinline__ unsigned short f2bf(float f) {
    union { float f; unsigned u; } v; v.f = f;
    unsigned r = (v.u + 0x7FFFu + ((v.u >> 16) & 1u)) >> 16;
    return (unsigned short)r;
}
__device__ __forceinline__ float bf2f(unsigned short u) {
    union { unsigned u; float f; } v; v.u = ((unsigned)u) << 16; return v.f;
}

// async global->LDS, 16B per lane; LDS dest = wave-uniform base + lane*16B.
__device__ __forceinline__ void gload16(const unsigned short* g, unsigned short* l) {
    __builtin_amdgcn_global_load_lds(
        (const __attribute__((address_space(1))) void*)g,
        (__attribute__((address_space(3))) void*)l, 16, 0, 0);
}

// Chunk = 16 rows x 32 ushorts (1 KiB). Lane i -> (row=i>>2, slot=i&3).
// Both-sides bank swizzle for K-tiles: source col = (slot ^ ((row>>1)&3))*8.
__device__ __forceinline__ int swz(int slot, int row) {
    return (slot ^ ((row >> 1) & 3)) * 8;
}
// Unswizzled chunked-tile index for 64x64 LDS tiles staged as 8 chunks.
__device__ __forceinline__ int tix(int ml, int jl) {
    return ((ml >> 4) * 2 + (jl >> 5)) * 512 + (ml & 15) * 32 + (jl & 31);
}

// Software grid barrier, cooperative-groups style:
// arrive = one device-scope atomicAdd per block; spin = RELAXED agent load
// (no per-poll cache invalidate -- the round-8 failure was acquire-per-poll
// emitting buffer_inv each iteration); one acquire fence after exit.
__device__ __forceinline__ void grid_sync(unsigned* cnt, unsigned* gen,
                                          unsigned nb, unsigned my)
{
    __syncthreads();
    if (threadIdx.x == 0) {
        __threadfence();                       // release
        if (atomicAdd(cnt, 1u) == nb - 1u) {
            atomicExch(cnt, 0u);
            __hip_atomic_store(gen, my + 1u, __ATOMIC_RELAXED,
                               __HIP_MEMORY_SCOPE_AGENT);
        } else {
            while (__hip_atomic_load(gen, __ATOMIC_RELAXED,
                                     __HIP_MEMORY_SCOPE_AGENT) <= my)
                __builtin_amdgcn_s_sleep(8);
        }
        __threadfence();                       // acquire (single buffer_inv)
    }
    __syncthreads();
}

// ---------------------------------------------------------------------------
// prep kernels
// ---------------------------------------------------------------------------
__global__ void cvt_f32_bf16(const float* __restrict__ src,
                             unsigned short* __restrict__ dst, int n)
{
    const int i = (blockIdx.x * blockDim.x + threadIdx.x) * 4;
    if (i >= n) return;
    const float4 v = *reinterpret_cast<const float4*>(src + i);
    ushort4 o;
    o.x = f2bf(v.x); o.y = f2bf(v.y); o.z = f2bf(v.z); o.w = f2bf(v.w);
    *reinterpret_cast<ushort4*>(dst + i) = o;
}

// all 5 weight transposes in one launch (tile jobs decoded from blockIdx)
__global__ void transpose_all(const float* __restrict__ W_ih,
                              const float* __restrict__ W_hh,
                              const float* __restrict__ Wx,
                              const float* __restrict__ U_iou,
                              const float* __restrict__ U_f,
                              unsigned short* __restrict__ WihT,
                              unsigned short* __restrict__ WhhT,
                              unsigned short* __restrict__ WxT,
                              unsigned short* __restrict__ UcombT,
                              int threeH, int I, int H,
                              int n1, int n2, int n3, int n4)
{
    int b = (int)blockIdx.x;
    const float* src; unsigned short* dst; int rows, cols;
    if (b < n1)      { src = W_ih;  dst = WihT;   rows = I; cols = threeH; }
    else if (b < n2) { src = W_hh;  dst = WhhT;   rows = H; cols = threeH; b -= n1; }
    else if (b < n3) { src = Wx;    dst = WxT;    rows = H; cols = 4 * H;  b -= n2; }
    else if (b < n4) { src = U_iou; dst = UcombT; rows = H; cols = threeH; b -= n3; }
    else { src = U_f; dst = UcombT + (size_t)threeH * H; rows = H; cols = H; b -= n4; }
    const int ncx = cols / 32;
    const int bc = (b % ncx) * 32, br = (b / ncx) * 32;
    __shared__ float tile[32][33];
    const int tx = threadIdx.x, ty = threadIdx.y;  // block (32,8)
    #pragma unroll
    for (int i = 0; i < 32; i += 8)
        tile[ty + i][tx] = src[(size_t)(br + ty + i) * cols + bc + tx];
    __syncthreads();
    #pragma unroll
    for (int i = 0; i < 32; i += 8)
        dst[(size_t)(bc + ty + i) * rows + br + tx] = f2bf(tile[tx][ty + i]);
}

// ---------------------------------------------------------------------------
// bf16-output GEMM: Cb[M][N](bf16) = A' @ BT[N][K]^T + bias (row-gather A').
// 1-D grid, XCD-CHUNKED remap. 128x128, 3-deep, stage-early, setprio.
// barclr: optional 16-word barrier-state clear by block 0 (free piggyback).
// ---------------------------------------------------------------------------
__global__ __launch_bounds__(256)
void gemm_bf16out(const unsigned short* __restrict__ A,
                  const unsigned short* __restrict__ BT,
                  const float* __restrict__ bias,
                  unsigned short* __restrict__ Cb, int M, int N, int K,
                  int ncols, int Mrows, int rstride, int tstride,
                  unsigned* __restrict__ barclr)
{
    const int nwg = (int)gridDim.x;
    const int l = ((int)blockIdx.x & 7) * (nwg >> 3) + ((int)blockIdx.x >> 3);
    const int m0 = (l / ncols) * 128, n0 = (l % ncols) * 128;
    const size_t abase = (size_t)(m0 % Mrows) * rstride
                       + (size_t)(m0 / Mrows) * tstride;
    const int tid = (int)threadIdx.x, lane = tid & 63, wid = tid >> 6;
    const int wm = wid >> 1, wn = wid & 1;
    const int fr = lane & 15, kg = lane >> 4;
    const int lrow = lane >> 2;
    const int scol = swz(lane & 3, lrow);

    __shared__ unsigned short smem[3 * 8192];

    f32x4 acc[4][4];
    #pragma unroll
    for (int i = 0; i < 4; ++i)
        #pragma unroll
        for (int j = 0; j < 4; ++j)
            acc[i][j] = (f32x4){0.f, 0.f, 0.f, 0.f};

    auto stage = [&](int buf, int kt) {
        const int k0 = kt * 32;
        unsigned short* base = &smem[buf * 8192];
        #pragma unroll
        for (int q = 0; q < 4; ++q) {
            const int c = wid * 4 + q;
            const unsigned short* g = (c < 8)
                ? A + abase + (size_t)(c * 16 + lrow) * rstride + k0 + scol
                : BT + (size_t)(n0 + (c - 8) * 16 + lrow) * K + k0 + scol;
            gload16(g, base + c * 512);
        }
    };

    const int nkt = K >> 5;
    stage(0, 0); stage(1, 1); stage(2, 2);
    int cur = 0;

    for (int kt = 0; kt < nkt; ++kt) {
        if (kt + 2 < nkt)      asm volatile("s_waitcnt vmcnt(8)" ::: "memory");
        else if (kt + 1 < nkt) asm volatile("s_waitcnt vmcnt(4)" ::: "memory");
        else                   asm volatile("s_waitcnt vmcnt(0)" ::: "memory");
        __builtin_amdgcn_s_barrier();

        const unsigned short* sb = &smem[cur * 8192];
        bf16x8 af[4], bf[4];
        #pragma unroll
        for (int mi = 0; mi < 4; ++mi) {
            const int row = wm * 64 + mi * 16 + fr;
            af[mi] = *reinterpret_cast<const bf16x8*>(&sb[row * 32 + swz(kg, row)]);
        }
        #pragma unroll
        for (int ni = 0; ni < 4; ++ni) {
            const int row = wn * 64 + ni * 16 + fr;
            bf[ni] = *reinterpret_cast<const bf16x8*>(&sb[4096 + row * 32 + swz(kg, row)]);
        }
        asm volatile("s_waitcnt lgkmcnt(0)" ::: "memory");
        __builtin_amdgcn_s_barrier();
        if (kt + 3 < nkt) stage(cur, kt + 3);

        __builtin_amdgcn_s_setprio(1);
        #pragma unroll
        for (int mi = 0; mi < 4; ++mi)
            #pragma unroll
            for (int ni = 0; ni < 4; ++ni)
                acc[mi][ni] = __builtin_amdgcn_mfma_f32_16x16x32_bf16(
                    af[mi], bf[ni], acc[mi][ni], 0, 0, 0);
        __builtin_amdgcn_s_setprio(0);
        cur = (cur == 2) ? 0 : cur + 1;
    }

    // bf16 output via padded LDS bounce ([128][132]) -> plain coalesced stores
    #pragma unroll
    for (int ni = 0; ni < 4; ++ni) {
        const int nl = wn * 64 + ni * 16 + fr;
        const float bv = bias[n0 + nl];
        #pragma unroll
        for (int mi = 0; mi < 4; ++mi)
            #pragma unroll
            for (int r = 0; r < 4; ++r) {
                const int ml = wm * 64 + mi * 16 + kg * 4 + r;
                smem[ml * 132 + nl] = f2bf(acc[mi][ni][r] + bv);
            }
    }
    __syncthreads();
    #pragma unroll
    for (int e = 0; e < 8; ++e) {
        const int id = tid + e * 256;          // 2048 chunks of 16B
        const int row = id >> 4, cw = id & 15;
        const int4 v = *reinterpret_cast<const int4*>(&smem[row * 132 + cw * 8]);
        *reinterpret_cast<int4*>(&Cb[(size_t)(m0 + row) * N + n0 + cw * 8]) = v;
    }
    if (barclr && blockIdx.x == 0 && tid < 16) barclr[tid] = 0;
}

// ---------------------------------------------------------------------------
// GRU step 0 (h=0): pure pointwise from gi (t-major; t=0 slice first).
// ---------------------------------------------------------------------------
__global__ void gru_step0(const unsigned short* __restrict__ gi,  // [L][N][1536]
                          unsigned short* __restrict__ hbo,
                          const float* __restrict__ b_hh)
{
    constexpr int H = 512, G3H = 1536;
    const int idx = blockIdx.x * blockDim.x + threadIdx.x;  // N*H/8 exact
    const int m = idx >> 6, jv = idx & 63;
    const size_t gb = (size_t)m * G3H + jv * 8;
    const bf16x8 gr8 = *reinterpret_cast<const bf16x8*>(gi + gb);
    const bf16x8 gz8 = *reinterpret_cast<const bf16x8*>(gi + gb + H);
    const bf16x8 gn8 = *reinterpret_cast<const bf16x8*>(gi + gb + 2 * H);
    bf16x8 o;
    #pragma unroll
    for (int k = 0; k < 8; ++k) {
        const int j = jv * 8 + k;
        const float r = sigf(bf2f((unsigned short)gr8[k]) + b_hh[j]);
        const float z = sigf(bf2f((unsigned short)gz8[k]) + b_hh[H + j]);
        const float n = tanhf_fast(bf2f((unsigned short)gn8[k]) + r * b_hh[2 * H + j]);
        o[k] = (short)f2bf((1.f - z) * n);
    }
    *reinterpret_cast<bf16x8*>(hbo + (size_t)m * H + jv * 8) = o;
}

// ---------------------------------------------------------------------------
// GRU step (recurrent part): acc = h @ W_hh; epilogue combines with gi and h.
// Tile 64x64, 4 waves 2x2. 3-BUFFER 3-deep pipeline, uniform vmcnt(8);
// epilogue tiles prefetched into the freed buffers.
// ---------------------------------------------------------------------------
__global__ __launch_bounds__(256, 3)
void gru_step(const unsigned short* __restrict__ giT,  // t's slice [N][1536]
              const unsigned short* __restrict__ hbi,
              unsigned short* __restrict__ hbo,
              const unsigned short* __restrict__ WhhT, // [1536][512]
              const float* __restrict__ b_hh)
{
    constexpr int H = 512, G3H = 1536;
    const int m0 = blockIdx.x * 64, j0 = blockIdx.y * 64;
    const int tid = (int)threadIdx.x, lane = tid & 63, wid = tid >> 6;
    const int wm = wid >> 1, wn = wid & 1;
    const int fr = lane & 15, kg = lane >> 4;
    const int lrow = lane >> 2;
    const int scol = swz(lane & 3, lrow);
    const int ucol = (lane & 3) * 8;

    __shared__ unsigned short smem[3 * 8192];

    f32x4 ar[2][2], az[2][2], ah[2][2];
    #pragma unroll
    for (int i = 0; i < 2; ++i)
        #pragma unroll
        for (int j = 0; j < 2; ++j) {
            ar[i][j] = (f32x4){0.f, 0.f, 0.f, 0.f};
            az[i][j] = (f32x4){0.f, 0.f, 0.f, 0.f};
            ah[i][j] = (f32x4){0.f, 0.f, 0.f, 0.f};
        }

    constexpr int nkt = H / 32;   // 16

    auto stage = [&](int buf, int kt) {
        const int k0 = kt * 32;
        unsigned short* base = &smem[buf * 8192];
        #pragma unroll
        for (int q = 0; q < 4; ++q) {
            const int c = wid * 4 + q;     // 16 chunks of 1 KiB
            if (c < 4) {
                const unsigned short* g =
                    hbi + (size_t)(m0 + c * 16 + lrow) * H + k0 + scol;
                gload16(g, base + c * 512);
            } else {
                const int gate = (c - 4) >> 2, rowg = (c - 4) & 3;
                const unsigned short* g =
                    WhhT + (size_t)(gate * H + j0 + rowg * 16 + lrow) * H + k0 + scol;
                gload16(g, base + c * 512);
            }
        }
    };
    auto stage_epi = [&](int ep) {
        unsigned short* base = &smem[(ep + 1) * 8192];
        #pragma unroll
        for (int q = 0; q < 4; ++q) {
            const int c = wid * 4 + q;            // 16 chunks
            const int part = c >> 3, cc = c & 7;
            const int rowg = cc >> 1, colg = cc & 1;
            const unsigned short* src;
            if (ep == 0)
                src = giT + (size_t)(m0 + rowg * 16 + lrow) * G3H
                          + part * H + j0 + colg * 32 + ucol;
            else if (part == 0)
                src = giT + (size_t)(m0 + rowg * 16 + lrow) * G3H
                          + 2 * H + j0 + colg * 32 + ucol;
            else
                src = hbi + (size_t)(m0 + rowg * 16 + lrow) * H
                          + j0 + colg * 32 + ucol;
            gload16(src, base + part * 4096 + cc * 512);
        }
    };

    stage(0, 0); stage(1, 1); stage(2, 2);
    int cur = 0;

    for (int kt = 0; kt < nkt; ++kt) {
        asm volatile("s_waitcnt vmcnt(8)" ::: "memory");
        __builtin_amdgcn_s_barrier();

        const unsigned short* sb = &smem[cur * 8192];
        bf16x8 af[2], bfr[2], bfz[2], bfn[2];
        #pragma unroll
        for (int mi = 0; mi < 2; ++mi) {
            const int row = wm * 32 + mi * 16 + fr;
            af[mi] = *reinterpret_cast<const bf16x8*>(&sb[row * 32 + swz(kg, row)]);
        }
        #pragma unroll
        for (int ni = 0; ni < 2; ++ni) {
            const int row = wn * 32 + ni * 16 + fr;
            const int sw = swz(kg, row);
            bfr[ni] = *reinterpret_cast<const bf16x8*>(&sb[2048 + (row) * 32 + sw]);
            bfz[ni] = *reinterpret_cast<const bf16x8*>(&sb[2048 + (64 + row) * 32 + sw]);
            bfn[ni] = *reinterpret_cast<const bf16x8*>(&sb[2048 + (128 + row) * 32 + sw]);
        }
        asm volatile("s_waitcnt lgkmcnt(0)" ::: "memory");
        __builtin_amdgcn_s_barrier();
        if (kt + 3 < nkt)       stage(cur, kt + 3);
        else if (kt == nkt - 3) stage_epi(0);
        else if (kt == nkt - 2) stage_epi(1);

        __builtin_amdgcn_s_setprio(1);
        #pragma unroll
        for (int mi = 0; mi < 2; ++mi)
            #pragma unroll
            for (int ni = 0; ni < 2; ++ni) {
                ar[mi][ni] = __builtin_amdgcn_mfma_f32_16x16x32_bf16(af[mi], bfr[ni], ar[mi][ni], 0, 0, 0);
                az[mi][ni] = __builtin_amdgcn_mfma_f32_16x16x32_bf16(af[mi], bfz[ni], az[mi][ni], 0, 0, 0);
                ah[mi][ni] = __builtin_amdgcn_mfma_f32_16x16x32_bf16(af[mi], bfn[ni], ah[mi][ni], 0, 0, 0);
            }
        __builtin_amdgcn_s_setprio(0);
        cur = (cur == 2) ? 0 : cur + 1;
    }

    asm volatile("s_waitcnt vmcnt(0)" ::: "memory");
    __builtin_amdgcn_s_barrier();

    unsigned short res[2][2][4];
    #pragma unroll
    for (int ni = 0; ni < 2; ++ni) {
        const int jl = wn * 32 + ni * 16 + fr;
        const int j = j0 + jl;
        const float bhr = b_hh[j], bhz = b_hh[H + j], bhn = b_hh[2 * H + j];
        #pragma unroll
        for (int mi = 0; mi < 2; ++mi) {
            #pragma unroll
            for (int r = 0; r < 4; ++r) {
                const int ml = wm * 32 + mi * 16 + kg * 4 + r;
                const int ix = tix(ml, jl);
                const float gr = bf2f(smem[8192 + ix]);
                const float gz = bf2f(smem[12288 + ix]);
                const float gn = bf2f(smem[16384 + ix]);
                const float hv = bf2f(smem[20480 + ix]);
                const float rg = sigf(ar[mi][ni][r] + gr + bhr);
                const float zg = sigf(az[mi][ni][r] + gz + bhz);
                const float ng = tanhf_fast(gn + rg * (ah[mi][ni][r] + bhn));
                res[ni][mi][r] = f2bf((1.f - zg) * ng + zg * hv);
            }
        }
    }

    #pragma unroll
    for (int ni = 0; ni < 2; ++ni) {
        const int jl = wn * 32 + ni * 16 + fr;
        #pragma unroll
        for (int mi = 0; mi < 2; ++mi)
            #pragma unroll
            for (int r = 0; r < 4; ++r) {
                const int ml = wm * 32 + mi * 16 + kg * 4 + r;
                smem[tix(ml, jl)] = res[ni][mi][r];
            }
    }
    __syncthreads();

    #pragma unroll
    for (int e = 0; e < 2; ++e) {
        const int id = tid + e * 256;         // 512 chunks of 16B
        const int ml = id >> 3, jw = id & 7;
        const int4 v = *reinterpret_cast<const int4*>(
            &smem[((ml >> 4) * 2 + (jw >> 2)) * 512 + (ml & 15) * 32 + (jw & 3) * 8]);
        *reinterpret_cast<int4*>(&hbo[(size_t)(m0 + ml) * H + j0 + jw * 8]) = v;
    }
}

// ---------------------------------------------------------------------------
// Fused tree phase: all D levels + output in ONE kernel. 512 blocks (4/CU
// capacity, 2x co-residency margin), grid barriers between phases.
// Per level: GEMM G = h_c @ [U_iou|U_f] (64x64 tiles, XCD-chunked, 4-deep)
// with atomic scatter -> sync -> pointwise update (512 blocks x 1024 elems;
// lvl=D-1 treats giou/fcs as zero and primes zeros; lvl>0 re-zeros) -> sync.
// ---------------------------------------------------------------------------
__global__ __launch_bounds__(256, 4)
void tree_fused(unsigned short* __restrict__ hb,        // bf16 tree h
                const unsigned short* __restrict__ UcombT,  // [2048][512]
                const unsigned short* __restrict__ xgb,     // [N][2048] bf16
                float* __restrict__ cT, float* __restrict__ hT,
                const int* __restrict__ parent,
                float* __restrict__ giou,                   // [PER][1536]
                float* __restrict__ fcs,                    // [PER][512]
                float* __restrict__ outp,
                int D, int PER, unsigned* __restrict__ bar)
{
    constexpr int H = 512, N4H = 2048, G3H = 1536;
    const int bx = (int)blockIdx.x, tid = (int)threadIdx.x;
    const int lane = tid & 63, wid = tid >> 6;
    const int wm = wid >> 1, wn = wid & 1;
    const int fr = lane & 15, kg = lane >> 4;
    const int lrow = lane >> 2;
    const int scol = swz(lane & 3, lrow);
    const int nwg = (int)gridDim.x;                        // 512
    const int l = (bx & 7) * (nwg >> 3) + (bx >> 3);
    const int gm0 = (l >> 5) * 64, gn0 = (l & 31) * 64;    // col fastest
    const int PH = PER * H;

    __shared__ unsigned short smem[4 * 4096];

    unsigned my = 0;

    for (int lvl = D - 1; lvl >= 0; --lvl) {
        const int pstart = lvl * PER;
        const int cstart = (lvl + 1) * PER;
        const bool has_children = (lvl < D - 1);

        if (has_children) {
            f32x4 acc[2][2];
            #pragma unroll
            for (int i = 0; i < 2; ++i)
                #pragma unroll
                for (int j = 0; j < 2; ++j)
                    acc[i][j] = (f32x4){0.f, 0.f, 0.f, 0.f};

            auto stage = [&](int buf, int kt) {
                const int k0 = kt * 32;
                unsigned short* base = &smem[buf * 4096];
                #pragma unroll
                for (int q = 0; q < 2; ++q) {
                    const int c = wid * 2 + q;   // 8 chunks
                    const unsigned short* g = (c < 4)
                        ? hb + (size_t)(cstart + gm0 + c * 16 + lrow) * H + k0 + scol
                        : UcombT + (size_t)(gn0 + (c - 4) * 16 + lrow) * H + k0 + scol;
                    gload16(g, base + c * 512);
                }
            };

            constexpr int nkt = H / 32;  // 16
            stage(0, 0); stage(1, 1); stage(2, 2); stage(3, 3);
            int cur = 0;

            for (int kt = 0; kt < nkt; ++kt) {
                if (kt + 3 < nkt)      asm volatile("s_waitcnt vmcnt(6)" ::: "memory");
                else if (kt + 2 < nkt) asm volatile("s_waitcnt vmcnt(4)" ::: "memory");
                else if (kt + 1 < nkt) asm volatile("s_waitcnt vmcnt(2)" ::: "memory");
                else                   asm volatile("s_waitcnt vmcnt(0)" ::: "memory");
                __builtin_amdgcn_s_barrier();

                const unsigned short* sb = &smem[cur * 4096];
                bf16x8 af[2], bf[2];
                #pragma unroll
                for (int mi = 0; mi < 2; ++mi) {
                    const int row = wm * 32 + mi * 16 + fr;
                    af[mi] = *reinterpret_cast<const bf16x8*>(&sb[row * 32 + swz(kg, row)]);
                }
                #pragma unroll
                for (int ni = 0; ni < 2; ++ni) {
                    const int row = wn * 32 + ni * 16 + fr;
                    bf[ni] = *reinterpret_cast<const bf16x8*>(&sb[2048 + row * 32 + swz(kg, row)]);
                }
                asm volatile("s_waitcnt lgkmcnt(0)" ::: "memory");
                __builtin_amdgcn_s_barrier();
                if (kt + 4 < nkt) stage(cur, kt + 4);

                __builtin_amdgcn_s_setprio(1);
                #pragma unroll
                for (int mi = 0; mi < 2; ++mi)
                    #pragma unroll
                    for (int ni = 0; ni < 2; ++ni)
                        acc[mi][ni] = __builtin_amdgcn_mfma_f32_16x16x32_bf16(
                            af[mi], bf[ni], acc[mi][ni], 0, 0, 0);
                __builtin_amdgcn_s_setprio(0);
                cur = (cur == 3) ? 0 : cur + 1;
            }

            if (gn0 < G3H) {
                #pragma unroll
                for (int mi = 0; mi < 2; ++mi)
                    #pragma unroll
                    for (int r = 0; r < 4; ++r) {
                        const int m = gm0 + wm * 32 + mi * 16 + kg * 4 + r;
                        const int p = parent[cstart + m] - pstart;
                        #pragma unroll
                        for (int ni = 0; ni < 2; ++ni) {
                            const int n = gn0 + wn * 32 + ni * 16 + fr;
                            atomicAdd(&giou[(size_t)p * G3H + n], acc[mi][ni][r]);
                        }
                    }
            } else {
                #pragma unroll
                for (int mi = 0; mi < 2; ++mi)
                    #pragma unroll
                    for (int r = 0; r < 4; ++r) {
                        const int m = gm0 + wm * 32 + mi * 16 + kg * 4 + r;
                        const int child = cstart + m;
                        const int p = parent[child];
                        #pragma unroll
                        for (int ni = 0; ni < 2; ++ni) {
                            const int jf = gn0 + wn * 32 + ni * 16 + fr - G3H;
                            const float f = sigf(acc[mi][ni][r] +
                                                 bf2f(xgb[(size_t)p * N4H + G3H + jf]));
                            atomicAdd(&fcs[(size_t)(p - pstart) * H + jf],
                                      f * cT[(size_t)child * H + jf]);
                        }
                    }
            }
            grid_sync(&bar[0], &bar[1], nwg, my++);
        }

        // ---- pointwise level update: 1024 elems/block ----
        #pragma unroll
        for (int e = 0; e < 4; ++e) {
            const int idx = bx * 1024 + e * 256 + tid;
            const int pi = idx >> 9, j = idx & (H - 1);
            const int p = pstart + pi;
            const size_t xb4 = (size_t)p * N4H;
            const size_t gb = (size_t)pi * G3H;
            float gv0 = 0.f, gv1 = 0.f, gv2 = 0.f, fv = 0.f;
            if (has_children) {
                gv0 = giou[gb + j]; gv1 = giou[gb + H + j];
                gv2 = giou[gb + 2 * H + j]; fv = fcs[idx];
            }
            const float ig = sigf(bf2f(xgb[xb4 + j]) + gv0);
            const float og = sigf(bf2f(xgb[xb4 + H + j]) + gv1);
            const float ug = tanhf_fast(bf2f(xgb[xb4 + 2 * H + j]) + gv2);
            const float cn = ig * ug + fv;
            const float hn = og * tanhf_fast(cn);
            if (lvl == 0) {
                outp[idx] = cn;
                outp[(size_t)PH + idx] = hn;
            } else {
                const size_t off = (size_t)p * H + j;
                cT[off] = cn;
                hT[off] = hn;
                hb[off] = f2bf(hn);
                giou[gb + j] = 0.f;
                giou[gb + H + j] = 0.f;
                giou[gb + 2 * H + j] = 0.f;
                fcs[idx] = 0.f;
            }
        }
        if (lvl > 0) grid_sync(&bar[0], &bar[1], nwg, my++);
    }
}

// ---------------------------------------------------------------------------
extern "C" void kernel_launch(void* const* d_in, const int* in_sizes, int n_in,
                              void* d_out, int out_size, void* d_ws, size_t ws_size,
                              hipStream_t stream)
{
    const float* x_seq = (const float*)d_in[0];
    const float* W_ih  = (const float*)d_in[1];
    const float* W_hh  = (const float*)d_in[2];
    const float* b_ih  = (const float*)d_in[3];
    const float* b_hh  = (const float*)d_in[4];
    const float* Wx    = (const float*)d_in[5];
    const float* bx    = (const float*)d_in[6];
    const float* U_iou = (const float*)d_in[7];
    const float* U_f   = (const float*)d_in[8];
    const int* parent  = (const int*)d_in[9];

    const int threeH = in_sizes[3];          // 1536
    const int H   = threeH / 3;              // 512
    const int I   = in_sizes[1] / threeH;    // 256
    const int N   = in_sizes[9];             // 8192
    const int L   = in_sizes[0] / (N * I);   // 8
    const int PER = in_sizes[11];            // 1024
    const int D   = N / PER;                 // 8

    const size_t NH = (size_t)N * H;
    const size_t PH = (size_t)PER * H;
    const size_t NG = (size_t)N * threeH;    // per-step gi slice elements

    // ---- workspace carve-up ----
    char* p = (char*)d_ws;
    const size_t xb_sz  = (size_t)N * L * I * 2;
    const size_t xgb_sz = (size_t)N * 4 * H * 2;
    const size_t zone_sz = xb_sz > xgb_sz ? xb_sz : xgb_sz;
    unsigned short* xb  = (unsigned short*)p;
    unsigned short* xgb = (unsigned short*)p;    p += zone_sz;
    unsigned short* gi  = (unsigned short*)p;    p += (size_t)N * L * threeH * 2;
    unsigned short* hb0 = (unsigned short*)p;    p += NH * 2;
    unsigned short* hb1 = (unsigned short*)p;    p += NH * 2;
    unsigned short* WihT = (unsigned short*)p;   p += (size_t)threeH * I * 2;
    unsigned short* WhhT = (unsigned short*)p;   p += (size_t)threeH * H * 2;
    unsigned short* WxT  = (unsigned short*)p;   p += (size_t)4 * H * H * 2;
    unsigned short* UcombT = (unsigned short*)p; p += (size_t)4 * H * H * 2;
    unsigned* bar = (unsigned*)p;                p += 64;
    if ((size_t)(p - (char*)d_ws) > ws_size) return;
    // tree-phase aliases inside gi region (gi dead post-GRU):
    float* cT   = (float*)gi;
    float* hT   = cT + NH;
    float* giou = hT + NH;
    float* fcs  = giou + PH * 3;

    // ---- prep (2 launches) ----
    {
        const int n = N * L * I;
        cvt_f32_bf16<<<(n / 4 + 255) / 256, 256, 0, stream>>>(x_seq, xb, n);
        const int n1 = (threeH / 32) * (I / 32);
        const int n2 = n1 + (threeH / 32) * (H / 32);
        const int n3 = n2 + (4 * H / 32) * (H / 32);
        const int n4 = n3 + (threeH / 32) * (H / 32);
        const int n5 = n4 + (H / 32) * (H / 32);
        transpose_all<<<n5, dim3(32, 8), 0, stream>>>(
            W_ih, W_hh, Wx, U_iou, U_f, WihT, WhhT, WxT, UcombT,
            threeH, I, H, n1, n2, n3, n4);
    }

    // ---- Phase 0: gi[t][m] = x[m][t]@Wih + b_ih (one big GEMM) ----
    gemm_bf16out<<<(N * L / 128) * (threeH / 128), 256, 0, stream>>>(
        xb, WihT, b_ih, gi, N * L, threeH, I, threeH / 128,
        N, L * I, I, nullptr);

    // ---- Phase 1: GRU recurrence. Step 0 is pointwise (h=0). ----
    gru_step0<<<(int)(NH / 8 / 256), 256, 0, stream>>>(gi, hb1, b_hh);
    {
        dim3 grid(N / 64, H / 64);
        for (int t = 1; t < L; ++t) {
            const unsigned short* hin = (t & 1) ? hb1 : hb0;
            unsigned short* hout = (t & 1) ? hb0 : hb1;
            gru_step<<<grid, 256, 0, stream>>>(gi + (size_t)t * NG, hin, hout,
                                               WhhT, b_hh);
        }
        // L even -> enc bf16 in hb0
    }

    // ---- Phase 2: xg(bf16) = enc @ Wx + bx; block 0 clears barrier state ----
    gemm_bf16out<<<(N / 128) * (4 * H / 128), 256, 0, stream>>>(
        hb0, WxT, bx, xgb, N, 4 * H, H, 4 * H / 128,
        N, H, 0, bar);

    // ---- Phase 3+4: fused tree (gi dead; cT/hT/giou/fcs alias it).
    //      lvl=D-1 primes giou/fcs zeros itself -> no memset needed. ----
    tree_fused<<<(PER / 64) * (4 * H / 64), 256, 0, stream>>>(
        hb1, UcombT, xgb, cT, hT, parent, giou, fcs, (float*)d_out,
        D, PER, bar);
}

// Round 18
// 472.805 us; speedup vs baseline: 2.1569x; 2.1569x over previous
//
#include <hip/hip_runtime.h>
#include <math.h>

typedef short bf16x8 __attribute__((ext_vector_type(8)));
typedef float f32x4 __attribute__((ext_vector_type(4)));

__device__ __forceinline__ float sigf(float x) {
    return __builtin_amdgcn_rcpf(1.f + __expf(-x));
}
__device__ __forceinline__ float tanhf_fast(float x) {
    const float e = __expf(2.f * x);
    return 1.f - 2.f * __builtin_amdgcn_rcpf(e + 1.f);
}

__device__ __forceinline__ unsigned short f2bf(float f) {
    union { float f; unsigned u; } v; v.f = f;
    unsigned r = (v.u + 0x7FFFu + ((v.u >> 16) & 1u)) >> 16;
    return (unsigned short)r;
}
__device__ __forceinline__ float bf2f(unsigned short u) {
    union { unsigned u; float f; } v; v.u = ((unsigned)u) << 16; return v.f;
}

// async global->LDS, 16B per lane; LDS dest = wave-uniform base + lane*16B.
__device__ __forceinline__ void gload16(const unsigned short* g, unsigned short* l) {
    __builtin_amdgcn_global_load_lds(
        (const __attribute__((address_space(1))) void*)g,
        (__attribute__((address_space(3))) void*)l, 16, 0, 0);
}

// Chunk = 16 rows x 32 ushorts (1 KiB). Lane i -> (row=i>>2, slot=i&3).
// Both-sides bank swizzle for K-tiles: source col = (slot ^ ((row>>1)&3))*8.
__device__ __forceinline__ int swz(int slot, int row) {
    return (slot ^ ((row >> 1) & 3)) * 8;
}
// Unswizzled chunked-tile index for 64x64 LDS tiles staged as 8 chunks.
__device__ __forceinline__ int tix(int ml, int jl) {
    return ((ml >> 4) * 2 + (jl >> 5)) * 512 + (ml & 15) * 32 + (jl & 31);
}

// ---------------------------------------------------------------------------
// prep kernels
// ---------------------------------------------------------------------------
__global__ void cvt_f32_bf16(const float* __restrict__ src,
                             unsigned short* __restrict__ dst, int n)
{
    const int i = (blockIdx.x * blockDim.x + threadIdx.x) * 4;
    if (i >= n) return;
    const float4 v = *reinterpret_cast<const float4*>(src + i);
    ushort4 o;
    o.x = f2bf(v.x); o.y = f2bf(v.y); o.z = f2bf(v.z); o.w = f2bf(v.w);
    *reinterpret_cast<ushort4*>(dst + i) = o;
}

__global__ void transpose_cvt(const float* __restrict__ src,
                              unsigned short* __restrict__ dst,
                              int rows, int cols)
{
    __shared__ float tile[32][33];
    const int bc = blockIdx.x * 32, br = blockIdx.y * 32;
    const int tx = threadIdx.x, ty = threadIdx.y;  // block (32,8)
    #pragma unroll
    for (int i = 0; i < 32; i += 8)
        tile[ty + i][tx] = src[(size_t)(br + ty + i) * cols + bc + tx];
    __syncthreads();
    #pragma unroll
    for (int i = 0; i < 32; i += 8)
        dst[(size_t)(bc + ty + i) * rows + br + tx] = f2bf(tile[tx][ty + i]);
}

// ---------------------------------------------------------------------------
// bf16-output GEMM: Cb[M][N](bf16) = A' @ BT[N][K]^T + bias, where A' row r
// reads A + (r%Mrows)*rstride + (r/Mrows)*tstride  (generalized row gather;
// identity when Mrows=M, rstride=K, tstride=0).
// 1-D grid, XCD-CHUNKED remap. 128x128, 3-deep, stage-early, setprio.
// PLAIN C stores (outputs re-read within ~300us -> keep cache-resident).
// ---------------------------------------------------------------------------
__global__ __launch_bounds__(256)
void gemm_bf16out(const unsigned short* __restrict__ A,
                  const unsigned short* __restrict__ BT,
                  const float* __restrict__ bias,
                  unsigned short* __restrict__ Cb, int M, int N, int K,
                  int ncols, int Mrows, int rstride, int tstride)
{
    const int nwg = (int)gridDim.x;
    const int l = ((int)blockIdx.x & 7) * (nwg >> 3) + ((int)blockIdx.x >> 3);
    const int m0 = (l / ncols) * 128, n0 = (l % ncols) * 128;
    const size_t abase = (size_t)(m0 % Mrows) * rstride
                       + (size_t)(m0 / Mrows) * tstride;
    const int tid = (int)threadIdx.x, lane = tid & 63, wid = tid >> 6;
    const int wm = wid >> 1, wn = wid & 1;
    const int fr = lane & 15, kg = lane >> 4;
    const int lrow = lane >> 2;
    const int scol = swz(lane & 3, lrow);

    __shared__ unsigned short smem[3 * 8192];

    f32x4 acc[4][4];
    #pragma unroll
    for (int i = 0; i < 4; ++i)
        #pragma unroll
        for (int j = 0; j < 4; ++j)
            acc[i][j] = (f32x4){0.f, 0.f, 0.f, 0.f};

    auto stage = [&](int buf, int kt) {
        const int k0 = kt * 32;
        unsigned short* base = &smem[buf * 8192];
        #pragma unroll
        for (int q = 0; q < 4; ++q) {
            const int c = wid * 4 + q;
            const unsigned short* g = (c < 8)
                ? A + abase + (size_t)(c * 16 + lrow) * rstride + k0 + scol
                : BT + (size_t)(n0 + (c - 8) * 16 + lrow) * K + k0 + scol;
            gload16(g, base + c * 512);
        }
    };

    const int nkt = K >> 5;
    stage(0, 0); stage(1, 1); stage(2, 2);
    int cur = 0;

    for (int kt = 0; kt < nkt; ++kt) {
        if (kt + 2 < nkt)      asm volatile("s_waitcnt vmcnt(8)" ::: "memory");
        else if (kt + 1 < nkt) asm volatile("s_waitcnt vmcnt(4)" ::: "memory");
        else                   asm volatile("s_waitcnt vmcnt(0)" ::: "memory");
        __builtin_amdgcn_s_barrier();

        const unsigned short* sb = &smem[cur * 8192];
        bf16x8 af[4], bf[4];
        #pragma unroll
        for (int mi = 0; mi < 4; ++mi) {
            const int row = wm * 64 + mi * 16 + fr;
            af[mi] = *reinterpret_cast<const bf16x8*>(&sb[row * 32 + swz(kg, row)]);
        }
        #pragma unroll
        for (int ni = 0; ni < 4; ++ni) {
            const int row = wn * 64 + ni * 16 + fr;
            bf[ni] = *reinterpret_cast<const bf16x8*>(&sb[4096 + row * 32 + swz(kg, row)]);
        }
        asm volatile("s_waitcnt lgkmcnt(0)" ::: "memory");
        __builtin_amdgcn_s_barrier();
        if (kt + 3 < nkt) stage(cur, kt + 3);

        __builtin_amdgcn_s_setprio(1);
        #pragma unroll
        for (int mi = 0; mi < 4; ++mi)
            #pragma unroll
            for (int ni = 0; ni < 4; ++ni)
                acc[mi][ni] = __builtin_amdgcn_mfma_f32_16x16x32_bf16(
                    af[mi], bf[ni], acc[mi][ni], 0, 0, 0);
        __builtin_amdgcn_s_setprio(0);
        cur = (cur == 2) ? 0 : cur + 1;
    }

    // bf16 output via padded LDS bounce ([128][132]) -> plain coalesced stores
    #pragma unroll
    for (int ni = 0; ni < 4; ++ni) {
        const int nl = wn * 64 + ni * 16 + fr;
        const float bv = bias[n0 + nl];
        #pragma unroll
        for (int mi = 0; mi < 4; ++mi)
            #pragma unroll
            for (int r = 0; r < 4; ++r) {
                const int ml = wm * 64 + mi * 16 + kg * 4 + r;
                smem[ml * 132 + nl] = f2bf(acc[mi][ni][r] + bv);
            }
    }
    __syncthreads();
    #pragma unroll
    for (int e = 0; e < 8; ++e) {
        const int id = tid + e * 256;          // 2048 chunks of 16B
        const int row = id >> 4, cw = id & 15;
        const int4 v = *reinterpret_cast<const int4*>(&smem[row * 132 + cw * 8]);
        *reinterpret_cast<int4*>(&Cb[(size_t)(m0 + row) * N + n0 + cw * 8]) = v;
    }
}

// ---------------------------------------------------------------------------
// GRU step 0 (h=0): pure pointwise from gi (t-major; t=0 slice is first).
// ---------------------------------------------------------------------------
__global__ void gru_step0(const unsigned short* __restrict__ gi,  // [L][N][1536]
                          unsigned short* __restrict__ hbo,
                          const float* __restrict__ b_hh)
{
    constexpr int H = 512, G3H = 1536;
    const int idx = blockIdx.x * blockDim.x + threadIdx.x;  // N*H/8 exact
    const int m = idx >> 6, jv = idx & 63;
    const size_t gb = (size_t)m * G3H + jv * 8;
    const bf16x8 gr8 = *reinterpret_cast<const bf16x8*>(gi + gb);
    const bf16x8 gz8 = *reinterpret_cast<const bf16x8*>(gi + gb + H);
    const bf16x8 gn8 = *reinterpret_cast<const bf16x8*>(gi + gb + 2 * H);
    bf16x8 o;
    #pragma unroll
    for (int k = 0; k < 8; ++k) {
        const int j = jv * 8 + k;
        const float r = sigf(bf2f((unsigned short)gr8[k]) + b_hh[j]);
        const float z = sigf(bf2f((unsigned short)gz8[k]) + b_hh[H + j]);
        const float n = tanhf_fast(bf2f((unsigned short)gn8[k]) + r * b_hh[2 * H + j]);
        o[k] = (short)f2bf((1.f - z) * n);
    }
    *reinterpret_cast<bf16x8*>(hbo + (size_t)m * H + jv * 8) = o;
}

// ---------------------------------------------------------------------------
// GRU step (recurrent part): acc = h @ W_hh; epilogue combines with gi and h.
// gi is t-major: step t's slice is contiguous [N][1536].
// Tile 64x64, 4 waves 2x2. 3-BUFFER 3-deep pipeline (48 KiB, 3 blocks/CU);
// uniform vmcnt(8); epilogue tiles prefetched into freed buffers.
// ---------------------------------------------------------------------------
__global__ __launch_bounds__(256, 3)
void gru_step(const unsigned short* __restrict__ giT,  // t's slice [N][1536]
              const unsigned short* __restrict__ hbi,
              unsigned short* __restrict__ hbo,
              const unsigned short* __restrict__ WhhT, // [1536][512]
              const float* __restrict__ b_hh)
{
    constexpr int H = 512, G3H = 1536;
    const int m0 = blockIdx.x * 64, j0 = blockIdx.y * 64;
    const int tid = (int)threadIdx.x, lane = tid & 63, wid = tid >> 6;
    const int wm = wid >> 1, wn = wid & 1;
    const int fr = lane & 15, kg = lane >> 4;
    const int lrow = lane >> 2;
    const int scol = swz(lane & 3, lrow);
    const int ucol = (lane & 3) * 8;

    __shared__ unsigned short smem[3 * 8192];

    f32x4 ar[2][2], az[2][2], ah[2][2];
    #pragma unroll
    for (int i = 0; i < 2; ++i)
        #pragma unroll
        for (int j = 0; j < 2; ++j) {
            ar[i][j] = (f32x4){0.f, 0.f, 0.f, 0.f};
            az[i][j] = (f32x4){0.f, 0.f, 0.f, 0.f};
            ah[i][j] = (f32x4){0.f, 0.f, 0.f, 0.f};
        }

    constexpr int nkt = H / 32;   // 16

    auto stage = [&](int buf, int kt) {
        const int k0 = kt * 32;
        unsigned short* base = &smem[buf * 8192];
        #pragma unroll
        for (int q = 0; q < 4; ++q) {
            const int c = wid * 4 + q;     // 16 chunks of 1 KiB
            if (c < 4) {
                const unsigned short* g =
                    hbi + (size_t)(m0 + c * 16 + lrow) * H + k0 + scol;
                gload16(g, base + c * 512);
            } else {
                const int gate = (c - 4) >> 2, rowg = (c - 4) & 3;
                const unsigned short* g =
                    WhhT + (size_t)(gate * H + j0 + rowg * 16 + lrow) * H + k0 + scol;
                gload16(g, base + c * 512);
            }
        }
    };
    // ep=0 -> {gi r, gi z} into buf1; ep=1 -> {gi n, hv} into buf2.
    auto stage_epi = [&](int ep) {
        unsigned short* base = &smem[(ep + 1) * 8192];
        #pragma unroll
        for (int q = 0; q < 4; ++q) {
            const int c = wid * 4 + q;            // 16 chunks
            const int part = c >> 3, cc = c & 7;  // 2 tiles of 8 chunks
            const int rowg = cc >> 1, colg = cc & 1;
            const unsigned short* src;
            if (ep == 0)
                src = giT + (size_t)(m0 + rowg * 16 + lrow) * G3H
                          + part * H + j0 + colg * 32 + ucol;
            else if (part == 0)
                src = giT + (size_t)(m0 + rowg * 16 + lrow) * G3H
                          + 2 * H + j0 + colg * 32 + ucol;
            else
                src = hbi + (size_t)(m0 + rowg * 16 + lrow) * H
                          + j0 + colg * 32 + ucol;
            gload16(src, base + part * 4096 + cc * 512);
        }
    };

    stage(0, 0); stage(1, 1); stage(2, 2);
    int cur = 0;

    for (int kt = 0; kt < nkt; ++kt) {
        asm volatile("s_waitcnt vmcnt(8)" ::: "memory");
        __builtin_amdgcn_s_barrier();

        const unsigned short* sb = &smem[cur * 8192];
        bf16x8 af[2], bfr[2], bfz[2], bfn[2];
        #pragma unroll
        for (int mi = 0; mi < 2; ++mi) {
            const int row = wm * 32 + mi * 16 + fr;
            af[mi] = *reinterpret_cast<const bf16x8*>(&sb[row * 32 + swz(kg, row)]);
        }
        #pragma unroll
        for (int ni = 0; ni < 2; ++ni) {
            const int row = wn * 32 + ni * 16 + fr;
            const int sw = swz(kg, row);
            bfr[ni] = *reinterpret_cast<const bf16x8*>(&sb[2048 + (row) * 32 + sw]);
            bfz[ni] = *reinterpret_cast<const bf16x8*>(&sb[2048 + (64 + row) * 32 + sw]);
            bfn[ni] = *reinterpret_cast<const bf16x8*>(&sb[2048 + (128 + row) * 32 + sw]);
        }
        asm volatile("s_waitcnt lgkmcnt(0)" ::: "memory");
        __builtin_amdgcn_s_barrier();
        if (kt + 3 < nkt)       stage(cur, kt + 3);
        else if (kt == nkt - 3) stage_epi(0);
        else if (kt == nkt - 2) stage_epi(1);

        __builtin_amdgcn_s_setprio(1);
        #pragma unroll
        for (int mi = 0; mi < 2; ++mi)
            #pragma unroll
            for (int ni = 0; ni < 2; ++ni) {
                ar[mi][ni] = __builtin_amdgcn_mfma_f32_16x16x32_bf16(af[mi], bfr[ni], ar[mi][ni], 0, 0, 0);
                az[mi][ni] = __builtin_amdgcn_mfma_f32_16x16x32_bf16(af[mi], bfz[ni], az[mi][ni], 0, 0, 0);
                ah[mi][ni] = __builtin_amdgcn_mfma_f32_16x16x32_bf16(af[mi], bfn[ni], ah[mi][ni], 0, 0, 0);
            }
        __builtin_amdgcn_s_setprio(0);
        cur = (cur == 2) ? 0 : cur + 1;
    }

    asm volatile("s_waitcnt vmcnt(0)" ::: "memory");
    __builtin_amdgcn_s_barrier();

    // ---- gates: gi r @8192, gi z @12288, gi n @16384, hv @20480 ----
    unsigned short res[2][2][4];
    #pragma unroll
    for (int ni = 0; ni < 2; ++ni) {
        const int jl = wn * 32 + ni * 16 + fr;
        const int j = j0 + jl;
        const float bhr = b_hh[j], bhz = b_hh[H + j], bhn = b_hh[2 * H + j];
        #pragma unroll
        for (int mi = 0; mi < 2; ++mi) {
            #pragma unroll
            for (int r = 0; r < 4; ++r) {
                const int ml = wm * 32 + mi * 16 + kg * 4 + r;
                const int ix = tix(ml, jl);
                const float gr = bf2f(smem[8192 + ix]);
                const float gz = bf2f(smem[12288 + ix]);
                const float gn = bf2f(smem[16384 + ix]);
                const float hv = bf2f(smem[20480 + ix]);
                const float rg = sigf(ar[mi][ni][r] + gr + bhr);
                const float zg = sigf(az[mi][ni][r] + gz + bhz);
                const float ng = tanhf_fast(gn + rg * (ah[mi][ni][r] + bhn));
                res[ni][mi][r] = f2bf((1.f - zg) * ng + zg * hv);
            }
        }
    }

    // ---- res -> buf0 out-tile, then coalesced stores ----
    #pragma unroll
    for (int ni = 0; ni < 2; ++ni) {
        const int jl = wn * 32 + ni * 16 + fr;
        #pragma unroll
        for (int mi = 0; mi < 2; ++mi)
            #pragma unroll
            for (int r = 0; r < 4; ++r) {
                const int ml = wm * 32 + mi * 16 + kg * 4 + r;
                smem[tix(ml, jl)] = res[ni][mi][r];
            }
    }
    __syncthreads();

    #pragma unroll
    for (int e = 0; e < 2; ++e) {
        const int id = tid + e * 256;         // 512 chunks of 16B
        const int ml = id >> 3, jw = id & 7;
        const int4 v = *reinterpret_cast<const int4*>(
            &smem[((ml >> 4) * 2 + (jw >> 2)) * 512 + (ml & 15) * 32 + (jw & 3) * 8]);
        *reinterpret_cast<int4*>(&hbo[(size_t)(m0 + ml) * H + j0 + jw * 8]) = v;
    }
}

// ---------------------------------------------------------------------------
// Tree level mega-GEMM: G = h_c @ [U_iou | U_f]. 64x64 tile, 512 blocks,
// XCD-chunked. 4-BUFFER 4-deep pipeline (32 KiB), stage-early, setprio.
// ---------------------------------------------------------------------------
__global__ __launch_bounds__(256, 4)
void tree_gemm(const unsigned short* __restrict__ hTb,
               const unsigned short* __restrict__ UcombT,  // [2048][512]
               const unsigned short* __restrict__ xgb,     // [N][2048] bf16
               const float* __restrict__ cT,               // [N][512]
               const int* __restrict__ parent,
               int cstart, int pstart,
               float* __restrict__ giou,                   // [PER][1536]
               float* __restrict__ fcs)                    // [PER][512]
{
    constexpr int H = 512, N4H = 2048, G3H = 1536;
    const int nwg = (int)gridDim.x;                        // 512
    const int l = ((int)blockIdx.x & 7) * (nwg >> 3) + ((int)blockIdx.x >> 3);
    const int m0 = (l >> 5) * 64, n0 = (l & 31) * 64;      // col fastest
    const int tid = (int)threadIdx.x, lane = tid & 63, wid = tid >> 6;
    const int wm = wid >> 1, wn = wid & 1;
    const int fr = lane & 15, kg = lane >> 4;
    const int lrow = lane >> 2;
    const int scol = swz(lane & 3, lrow);

    __shared__ unsigned short smem[4 * 4096];

    f32x4 acc[2][2];
    #pragma unroll
    for (int i = 0; i < 2; ++i)
        #pragma unroll
        for (int j = 0; j < 2; ++j)
            acc[i][j] = (f32x4){0.f, 0.f, 0.f, 0.f};

    auto stage = [&](int buf, int kt) {
        const int k0 = kt * 32;
        unsigned short* base = &smem[buf * 4096];
        #pragma unroll
        for (int q = 0; q < 2; ++q) {
            const int c = wid * 2 + q;   // 8 chunks
            const unsigned short* g = (c < 4)
                ? hTb + (size_t)(cstart + m0 + c * 16 + lrow) * H + k0 + scol
                : UcombT + (size_t)(n0 + (c - 4) * 16 + lrow) * H + k0 + scol;
            gload16(g, base + c * 512);
        }
    };

    constexpr int nkt = H / 32;  // 16
    stage(0, 0); stage(1, 1); stage(2, 2); stage(3, 3);
    int cur = 0;

    for (int kt = 0; kt < nkt; ++kt) {
        if (kt + 3 < nkt)      asm volatile("s_waitcnt vmcnt(6)" ::: "memory");
        else if (kt + 2 < nkt) asm volatile("s_waitcnt vmcnt(4)" ::: "memory");
        else if (kt + 1 < nkt) asm volatile("s_waitcnt vmcnt(2)" ::: "memory");
        else                   asm volatile("s_waitcnt vmcnt(0)" ::: "memory");
        __builtin_amdgcn_s_barrier();

        const unsigned short* sb = &smem[cur * 4096];
        bf16x8 af[2], bf[2];
        #pragma unroll
        for (int mi = 0; mi < 2; ++mi) {
            const int row = wm * 32 + mi * 16 + fr;
            af[mi] = *reinterpret_cast<const bf16x8*>(&sb[row * 32 + swz(kg, row)]);
        }
        #pragma unroll
        for (int ni = 0; ni < 2; ++ni) {
            const int row = wn * 32 + ni * 16 + fr;
            bf[ni] = *reinterpret_cast<const bf16x8*>(&sb[2048 + row * 32 + swz(kg, row)]);
        }
        asm volatile("s_waitcnt lgkmcnt(0)" ::: "memory");
        __builtin_amdgcn_s_barrier();
        if (kt + 4 < nkt) stage(cur, kt + 4);

        __builtin_amdgcn_s_setprio(1);
        #pragma unroll
        for (int mi = 0; mi < 2; ++mi)
            #pragma unroll
            for (int ni = 0; ni < 2; ++ni)
                acc[mi][ni] = __builtin_amdgcn_mfma_f32_16x16x32_bf16(
                    af[mi], bf[ni], acc[mi][ni], 0, 0, 0);
        __builtin_amdgcn_s_setprio(0);
        cur = (cur == 3) ? 0 : cur + 1;
    }

    if (n0 < G3H) {
        #pragma unroll
        for (int mi = 0; mi < 2; ++mi)
            #pragma unroll
            for (int r = 0; r < 4; ++r) {
                const int m = m0 + wm * 32 + mi * 16 + kg * 4 + r;
                const int p = parent[cstart + m] - pstart;
                #pragma unroll
                for (int ni = 0; ni < 2; ++ni) {
                    const int n = n0 + wn * 32 + ni * 16 + fr;
                    atomicAdd(&giou[(size_t)p * G3H + n], acc[mi][ni][r]);
                }
            }
    } else {
        #pragma unroll
        for (int mi = 0; mi < 2; ++mi)
            #pragma unroll
            for (int r = 0; r < 4; ++r) {
                const int m = m0 + wm * 32 + mi * 16 + kg * 4 + r;
                const int child = cstart + m;
                const int p = parent[child];
                #pragma unroll
                for (int ni = 0; ni < 2; ++ni) {
                    const int jf = n0 + wn * 32 + ni * 16 + fr - G3H;
                    const float f = sigf(acc[mi][ni][r] +
                                         bf2f(xgb[(size_t)p * N4H + G3H + jf]));
                    atomicAdd(&fcs[(size_t)(p - pstart) * H + jf],
                              f * cT[(size_t)child * H + jf]);
                }
            }
    }
}

// ---------------------------------------------------------------------------
// level update; re-zeros its exclusive giou/fcs slots; at the root level
// (outp != nullptr) writes the kernel output directly (root_ids = arange).
// ---------------------------------------------------------------------------
__global__ void level_update(const unsigned short* __restrict__ xgb,
                             float* __restrict__ giou,
                             float* __restrict__ fcs,
                             float* __restrict__ cT, float* __restrict__ hT,
                             unsigned short* __restrict__ hb, int pstart,
                             float* __restrict__ outp, int PH)
{
    constexpr int H = 512, N4H = 2048, G3H = 1536;
    const int idx = blockIdx.x * blockDim.x + threadIdx.x;  // PER*H exact
    const int pi = idx >> 9, j = idx & (H - 1);
    const int p = pstart + pi;
    const size_t xb4 = (size_t)p * N4H;
    const size_t gb = (size_t)pi * G3H;
    const float ig = sigf(bf2f(xgb[xb4 + j]) + giou[gb + j]);
    const float og = sigf(bf2f(xgb[xb4 + H + j]) + giou[gb + H + j]);
    const float ug = tanhf_fast(bf2f(xgb[xb4 + 2 * H + j]) + giou[gb + 2 * H + j]);
    const float cn = ig * ug + fcs[idx];
    const float hn = og * tanhf_fast(cn);
    if (outp) {
        outp[idx] = cn;
        outp[(size_t)PH + idx] = hn;
    } else {
        const size_t off = (size_t)p * H + j;
        cT[off] = cn;
        hT[off] = hn;
        hb[off] = f2bf(hn);
        giou[gb + j] = 0.f;
        giou[gb + H + j] = 0.f;
        giou[gb + 2 * H + j] = 0.f;
        fcs[idx] = 0.f;
    }
}

// ---------------------------------------------------------------------------
extern "C" void kernel_launch(void* const* d_in, const int* in_sizes, int n_in,
                              void* d_out, int out_size, void* d_ws, size_t ws_size,
                              hipStream_t stream)
{
    const float* x_seq = (const float*)d_in[0];
    const float* W_ih  = (const float*)d_in[1];
    const float* W_hh  = (const float*)d_in[2];
    const float* b_ih  = (const float*)d_in[3];
    const float* b_hh  = (const float*)d_in[4];
    const float* Wx    = (const float*)d_in[5];
    const float* bx    = (const float*)d_in[6];
    const float* U_iou = (const float*)d_in[7];
    const float* U_f   = (const float*)d_in[8];
    const int* parent  = (const int*)d_in[9];

    const int threeH = in_sizes[3];          // 1536
    const int H   = threeH / 3;              // 512
    const int I   = in_sizes[1] / threeH;    // 256
    const int N   = in_sizes[9];             // 8192
    const int L   = in_sizes[0] / (N * I);   // 8
    const int PER = in_sizes[11];            // 1024
    const int D   = N / PER;                 // 8

    const size_t NH = (size_t)N * H;
    const size_t PH = (size_t)PER * H;
    const size_t NG = (size_t)N * threeH;    // per-step gi slice elements

    // ---- workspace carve-up ----
    char* p = (char*)d_ws;
    const size_t xb_sz  = (size_t)N * L * I * 2;
    const size_t xgb_sz = (size_t)N * 4 * H * 2;
    const size_t zone_sz = xb_sz > xgb_sz ? xb_sz : xgb_sz;
    unsigned short* xb  = (unsigned short*)p;
    unsigned short* xgb = (unsigned short*)p;    p += zone_sz;
    unsigned short* gi  = (unsigned short*)p;    p += (size_t)N * L * threeH * 2;
    unsigned short* hb0 = (unsigned short*)p;    p += NH * 2;
    unsigned short* hb1 = (unsigned short*)p;    p += NH * 2;
    unsigned short* WihT = (unsigned short*)p;   p += (size_t)threeH * I * 2;
    unsigned short* WhhT = (unsigned short*)p;   p += (size_t)threeH * H * 2;
    unsigned short* WxT  = (unsigned short*)p;   p += (size_t)4 * H * H * 2;
    unsigned short* UcombT = (unsigned short*)p; p += (size_t)4 * H * H * 2;
    if ((size_t)(p - (char*)d_ws) > ws_size) return;
    // tree-phase aliases inside gi region (gi dead post-GRU):
    float* cT   = (float*)gi;
    float* hT   = cT + NH;
    float* giou = hT + NH;
    float* fcs  = giou + PH * 3;

    // ---- prep ----
    {
        const int n = N * L * I;
        cvt_f32_bf16<<<(n / 4 + 255) / 256, 256, 0, stream>>>(x_seq, xb, n);
        dim3 blk(32, 8);
        transpose_cvt<<<dim3(threeH / 32, I / 32), blk, 0, stream>>>(W_ih, WihT, I, threeH);
        transpose_cvt<<<dim3(threeH / 32, H / 32), blk, 0, stream>>>(W_hh, WhhT, H, threeH);
        transpose_cvt<<<dim3(4 * H / 32, H / 32), blk, 0, stream>>>(Wx, WxT, H, 4 * H);
        transpose_cvt<<<dim3(threeH / 32, H / 32), blk, 0, stream>>>(U_iou, UcombT, H, threeH);
        transpose_cvt<<<dim3(H / 32, H / 32), blk, 0, stream>>>(
            U_f, UcombT + (size_t)threeH * H, H, H);
    }

    // ---- Phase 0: gi[t][m] = x[m][t]@Wih + b_ih (one big GEMM, row-gather
    //      A addressing: row r -> xb + (r%N)*L*I + (r/N)*I) ----
    gemm_bf16out<<<(N * L / 128) * (threeH / 128), 256, 0, stream>>>(
        xb, WihT, b_ih, gi, N * L, threeH, I, threeH / 128,
        N, L * I, I);

    // ---- Phase 1: GRU recurrence. Step 0 is pointwise (h=0). ----
    gru_step0<<<(int)(NH / 8 / 256), 256, 0, stream>>>(gi, hb1, b_hh);
    {
        dim3 grid(N / 64, H / 64);
        for (int t = 1; t < L; ++t) {
            const unsigned short* hin = (t & 1) ? hb1 : hb0;
            unsigned short* hout = (t & 1) ? hb0 : hb1;
            gru_step<<<grid, 256, 0, stream>>>(gi + (size_t)t * NG, hin, hout,
                                               WhhT, b_hh);
        }
        // L even -> enc bf16 in hb0
    }

    // ---- Phase 2: xg(bf16) = enc @ Wx + bx ----
    gemm_bf16out<<<(N / 128) * (4 * H / 128), 256, 0, stream>>>(
        hb0, WxT, bx, xgb, N, 4 * H, H, 4 * H / 128,
        N, H, 0);

    // ---- Phase 3: tree levels (gi dead; cT/hT/giou/fcs alias it) ----
    hipMemsetAsync(giou, 0, PH * 4 * 4, stream);   // giou + fcs (contiguous)
    unsigned short* hTb = hb1;
    const int pw_blocks = (int)(PH / 256);

    for (int lvl = D - 1; lvl >= 0; --lvl) {
        const int pstart = lvl * PER;
        const int cstart = (lvl + 1) * PER;

        if (lvl < D - 1)
            tree_gemm<<<(PER / 64) * (4 * H / 64), 256, 0, stream>>>(
                hTb, UcombT, xgb, cT, parent, cstart, pstart, giou, fcs);

        level_update<<<pw_blocks, 256, 0, stream>>>(
            xgb, giou, fcs, cT, hT, hTb, pstart,
            (lvl == 0) ? (float*)d_out : nullptr, (int)PH);
    }
}

// Round 19
// 460.577 us; speedup vs baseline: 2.2142x; 1.0265x over previous
//
#include <hip/hip_runtime.h>
#include <math.h>

typedef short bf16x8 __attribute__((ext_vector_type(8)));
typedef float f32x4 __attribute__((ext_vector_type(4)));

__device__ __forceinline__ float sigf(float x) {
    return __builtin_amdgcn_rcpf(1.f + __expf(-x));
}
__device__ __forceinline__ float tanhf_fast(float x) {
    const float e = __expf(2.f * x);
    return 1.f - 2.f * __builtin_amdgcn_rcpf(e + 1.f);
}

__device__ __forceinline__ unsigned short f2bf(float f) {
    union { float f; unsigned u; } v; v.f = f;
    unsigned r = (v.u + 0x7FFFu + ((v.u >> 16) & 1u)) >> 16;
    return (unsigned short)r;
}
__device__ __forceinline__ float bf2f(unsigned short u) {
    union { unsigned u; float f; } v; v.u = ((unsigned)u) << 16; return v.f;
}

// async global->LDS, 16B per lane; LDS dest = wave-uniform base + lane*16B.
__device__ __forceinline__ void gload16(const unsigned short* g, unsigned short* l) {
    __builtin_amdgcn_global_load_lds(
        (const __attribute__((address_space(1))) void*)g,
        (__attribute__((address_space(3))) void*)l, 16, 0, 0);
}

// Chunk = 16 rows x 32 ushorts (1 KiB). Lane i -> (row=i>>2, slot=i&3).
// Both-sides bank swizzle for K-tiles: source col = (slot ^ ((row>>1)&3))*8.
__device__ __forceinline__ int swz(int slot, int row) {
    return (slot ^ ((row >> 1) & 3)) * 8;
}
// Unswizzled chunked-tile index for 64x64 tiles staged as 8 chunks.
__device__ __forceinline__ int tix(int ml, int jl) {
    return ((ml >> 4) * 2 + (jl >> 5)) * 512 + (ml & 15) * 32 + (jl & 31);
}
// Same for 128x64 tiles staged as 16 chunks.
__device__ __forceinline__ int tix128(int ml, int jl) {
    return ((ml >> 4) * 2 + (jl >> 5)) * 512 + (ml & 15) * 32 + (jl & 31);
}

// ---------------------------------------------------------------------------
// prep kernels
// ---------------------------------------------------------------------------
__global__ void cvt_f32_bf16(const float* __restrict__ src,
                             unsigned short* __restrict__ dst, int n)
{
    const int i = (blockIdx.x * blockDim.x + threadIdx.x) * 4;
    if (i >= n) return;
    const float4 v = *reinterpret_cast<const float4*>(src + i);
    ushort4 o;
    o.x = f2bf(v.x); o.y = f2bf(v.y); o.z = f2bf(v.z); o.w = f2bf(v.w);
    *reinterpret_cast<ushort4*>(dst + i) = o;
}

__global__ void transpose_cvt(const float* __restrict__ src,
                              unsigned short* __restrict__ dst,
                              int rows, int cols)
{
    __shared__ float tile[32][33];
    const int bc = blockIdx.x * 32, br = blockIdx.y * 32;
    const int tx = threadIdx.x, ty = threadIdx.y;  // block (32,8)
    #pragma unroll
    for (int i = 0; i < 32; i += 8)
        tile[ty + i][tx] = src[(size_t)(br + ty + i) * cols + bc + tx];
    __syncthreads();
    #pragma unroll
    for (int i = 0; i < 32; i += 8)
        dst[(size_t)(bc + ty + i) * rows + br + tx] = f2bf(tile[tx][ty + i]);
}

// ---------------------------------------------------------------------------
// bf16-output GEMM (unchanged): Cb = A' @ BT^T + bias, row-gather A'.
// 1-D grid, XCD-CHUNKED remap. 128x128, 3-deep, stage-early, setprio.
// ---------------------------------------------------------------------------
__global__ __launch_bounds__(256)
void gemm_bf16out(const unsigned short* __restrict__ A,
                  const unsigned short* __restrict__ BT,
                  const float* __restrict__ bias,
                  unsigned short* __restrict__ Cb, int M, int N, int K,
                  int ncols, int Mrows, int rstride, int tstride)
{
    const int nwg = (int)gridDim.x;
    const int l = ((int)blockIdx.x & 7) * (nwg >> 3) + ((int)blockIdx.x >> 3);
    const int m0 = (l / ncols) * 128, n0 = (l % ncols) * 128;
    const size_t abase = (size_t)(m0 % Mrows) * rstride
                       + (size_t)(m0 / Mrows) * tstride;
    const int tid = (int)threadIdx.x, lane = tid & 63, wid = tid >> 6;
    const int wm = wid >> 1, wn = wid & 1;
    const int fr = lane & 15, kg = lane >> 4;
    const int lrow = lane >> 2;
    const int scol = swz(lane & 3, lrow);

    __shared__ unsigned short smem[3 * 8192];

    f32x4 acc[4][4];
    #pragma unroll
    for (int i = 0; i < 4; ++i)
        #pragma unroll
        for (int j = 0; j < 4; ++j)
            acc[i][j] = (f32x4){0.f, 0.f, 0.f, 0.f};

    auto stage = [&](int buf, int kt) {
        const int k0 = kt * 32;
        unsigned short* base = &smem[buf * 8192];
        #pragma unroll
        for (int q = 0; q < 4; ++q) {
            const int c = wid * 4 + q;
            const unsigned short* g = (c < 8)
                ? A + abase + (size_t)(c * 16 + lrow) * rstride + k0 + scol
                : BT + (size_t)(n0 + (c - 8) * 16 + lrow) * K + k0 + scol;
            gload16(g, base + c * 512);
        }
    };

    const int nkt = K >> 5;
    stage(0, 0); stage(1, 1); stage(2, 2);
    int cur = 0;

    for (int kt = 0; kt < nkt; ++kt) {
        if (kt + 2 < nkt)      asm volatile("s_waitcnt vmcnt(8)" ::: "memory");
        else if (kt + 1 < nkt) asm volatile("s_waitcnt vmcnt(4)" ::: "memory");
        else                   asm volatile("s_waitcnt vmcnt(0)" ::: "memory");
        __builtin_amdgcn_s_barrier();

        const unsigned short* sb = &smem[cur * 8192];
        bf16x8 af[4], bf[4];
        #pragma unroll
        for (int mi = 0; mi < 4; ++mi) {
            const int row = wm * 64 + mi * 16 + fr;
            af[mi] = *reinterpret_cast<const bf16x8*>(&sb[row * 32 + swz(kg, row)]);
        }
        #pragma unroll
        for (int ni = 0; ni < 4; ++ni) {
            const int row = wn * 64 + ni * 16 + fr;
            bf[ni] = *reinterpret_cast<const bf16x8*>(&sb[4096 + row * 32 + swz(kg, row)]);
        }
        asm volatile("s_waitcnt lgkmcnt(0)" ::: "memory");
        __builtin_amdgcn_s_barrier();
        if (kt + 3 < nkt) stage(cur, kt + 3);

        __builtin_amdgcn_s_setprio(1);
        #pragma unroll
        for (int mi = 0; mi < 4; ++mi)
            #pragma unroll
            for (int ni = 0; ni < 4; ++ni)
                acc[mi][ni] = __builtin_amdgcn_mfma_f32_16x16x32_bf16(
                    af[mi], bf[ni], acc[mi][ni], 0, 0, 0);
        __builtin_amdgcn_s_setprio(0);
        cur = (cur == 2) ? 0 : cur + 1;
    }

    #pragma unroll
    for (int ni = 0; ni < 4; ++ni) {
        const int nl = wn * 64 + ni * 16 + fr;
        const float bv = bias[n0 + nl];
        #pragma unroll
        for (int mi = 0; mi < 4; ++mi)
            #pragma unroll
            for (int r = 0; r < 4; ++r) {
                const int ml = wm * 64 + mi * 16 + kg * 4 + r;
                smem[ml * 132 + nl] = f2bf(acc[mi][ni][r] + bv);
            }
    }
    __syncthreads();
    #pragma unroll
    for (int e = 0; e < 8; ++e) {
        const int id = tid + e * 256;          // 2048 chunks of 16B
        const int row = id >> 4, cw = id & 15;
        const int4 v = *reinterpret_cast<const int4*>(&smem[row * 132 + cw * 8]);
        *reinterpret_cast<int4*>(&Cb[(size_t)(m0 + row) * N + n0 + cw * 8]) = v;
    }
}

// ---------------------------------------------------------------------------
// GRU step 0 (h=0): pure pointwise from gi (t-major; t=0 slice is first).
// ---------------------------------------------------------------------------
__global__ void gru_step0(const unsigned short* __restrict__ gi,  // [L][N][1536]
                          unsigned short* __restrict__ hbo,
                          const float* __restrict__ b_hh)
{
    constexpr int H = 512, G3H = 1536;
    const int idx = blockIdx.x * blockDim.x + threadIdx.x;  // N*H/8 exact
    const int m = idx >> 6, jv = idx & 63;
    const size_t gb = (size_t)m * G3H + jv * 8;
    const bf16x8 gr8 = *reinterpret_cast<const bf16x8*>(gi + gb);
    const bf16x8 gz8 = *reinterpret_cast<const bf16x8*>(gi + gb + H);
    const bf16x8 gn8 = *reinterpret_cast<const bf16x8*>(gi + gb + 2 * H);
    bf16x8 o;
    #pragma unroll
    for (int k = 0; k < 8; ++k) {
        const int j = jv * 8 + k;
        const float r = sigf(bf2f((unsigned short)gr8[k]) + b_hh[j]);
        const float z = sigf(bf2f((unsigned short)gz8[k]) + b_hh[H + j]);
        const float n = tanhf_fast(bf2f((unsigned short)gn8[k]) + r * b_hh[2 * H + j]);
        o[k] = (short)f2bf((1.f - z) * n);
    }
    *reinterpret_cast<bf16x8*>(hbo + (size_t)m * H + jv * 8) = o;
}

// ---------------------------------------------------------------------------
// GRU step (recurrent part): acc = h @ W_hh; epilogue combines with gi and h.
// Tile 128(m) x 64(j); grid (64,8) = 512 blocks = EXACTLY 2/CU (one full
// dispatch wave -- fixes the 1024@3/CU ragged tail). 4 waves 2x2; each wave
// 64 rows x 32 cols x 3 gates = 24 MFMA/phase.
// LDS 64 KiB: 3 x 20 KiB buffers (A[128][32] @0, B[3][64][32] @4096 ushorts).
// 3-deep pipeline, 5 chunks/wave/phase. Epilogue gi tiles prefetched into
// buffers as they free: gi_r->buf1@kt13, gi_z->buf2@kt14, gi_n->buf0@kt15
// (vmcnt ladder 10/9/8); hv read direct from global (L2-hot, was A operand).
// ---------------------------------------------------------------------------
__global__ __launch_bounds__(256, 2)
void gru_step(const unsigned short* __restrict__ giT,  // t's slice [N][1536]
              const unsigned short* __restrict__ hbi,
              unsigned short* __restrict__ hbo,
              const unsigned short* __restrict__ WhhT, // [1536][512]
              const float* __restrict__ b_hh)
{
    constexpr int H = 512, G3H = 1536;
    const int m0 = blockIdx.x * 128, j0 = blockIdx.y * 64;
    const int tid = (int)threadIdx.x, lane = tid & 63, wid = tid >> 6;
    const int wm = wid >> 1, wn = wid & 1;
    const int fr = lane & 15, kg = lane >> 4;
    const int lrow = lane >> 2;
    const int scol = swz(lane & 3, lrow);
    const int ucol = (lane & 3) * 8;

    __shared__ unsigned short smem[3 * 10240 + 2048];   // 64 KiB

    f32x4 ar[4][2], az[4][2], ah[4][2];
    #pragma unroll
    for (int i = 0; i < 4; ++i)
        #pragma unroll
        for (int j = 0; j < 2; ++j) {
            ar[i][j] = (f32x4){0.f, 0.f, 0.f, 0.f};
            az[i][j] = (f32x4){0.f, 0.f, 0.f, 0.f};
            ah[i][j] = (f32x4){0.f, 0.f, 0.f, 0.f};
        }

    constexpr int nkt = H / 32;   // 16

    // 20 chunks: 0-7 A rows (128x32), 8-19 B gates (3 x 64x32)
    auto stage = [&](int buf, int kt) {
        const int k0 = kt * 32;
        unsigned short* base = &smem[buf * 10240];
        #pragma unroll
        for (int q = 0; q < 5; ++q) {
            const int c = wid * 5 + q;
            if (c < 8) {
                const unsigned short* g =
                    hbi + (size_t)(m0 + c * 16 + lrow) * H + k0 + scol;
                gload16(g, base + c * 512);
            } else {
                const int bc = c - 8, gate = bc >> 2, rowg = bc & 3;
                const unsigned short* g =
                    WhhT + (size_t)(gate * H + j0 + rowg * 16 + lrow) * H + k0 + scol;
                gload16(g, base + c * 512);
            }
        }
    };
    // epilogue gi tile g (128x64 = 16 chunks, 4/wave) into buffer `buf`
    auto stage_epi = [&](int buf, int g) {
        unsigned short* base = &smem[buf * 10240];
        #pragma unroll
        for (int q = 0; q < 4; ++q) {
            const int c = wid * 4 + q;            // 16 chunks
            const int rowg = c >> 1, colg = c & 1;
            const unsigned short* src =
                giT + (size_t)(m0 + rowg * 16 + lrow) * G3H
                    + g * H + j0 + colg * 32 + ucol;
            gload16(src, base + c * 512);
        }
    };

    stage(0, 0); stage(1, 1); stage(2, 2);
    int cur = 0;

    for (int kt = 0; kt < nkt; ++kt) {
        if (kt <= nkt - 3)      asm volatile("s_waitcnt vmcnt(10)" ::: "memory");
        else if (kt == nkt - 2) asm volatile("s_waitcnt vmcnt(9)" ::: "memory");
        else                    asm volatile("s_waitcnt vmcnt(8)" ::: "memory");
        __builtin_amdgcn_s_barrier();

        const unsigned short* sb = &smem[cur * 10240];
        bf16x8 af[4], bfr[2], bfz[2], bfn[2];
        #pragma unroll
        for (int mi = 0; mi < 4; ++mi) {
            const int row = wm * 64 + mi * 16 + fr;
            af[mi] = *reinterpret_cast<const bf16x8*>(&sb[row * 32 + swz(kg, row)]);
        }
        #pragma unroll
        for (int ni = 0; ni < 2; ++ni) {
            const int row = wn * 32 + ni * 16 + fr;
            const int sw = swz(kg, row);
            bfr[ni] = *reinterpret_cast<const bf16x8*>(&sb[4096 + (row) * 32 + sw]);
            bfz[ni] = *reinterpret_cast<const bf16x8*>(&sb[4096 + (64 + row) * 32 + sw]);
            bfn[ni] = *reinterpret_cast<const bf16x8*>(&sb[4096 + (128 + row) * 32 + sw]);
        }
        asm volatile("s_waitcnt lgkmcnt(0)" ::: "memory");
        __builtin_amdgcn_s_barrier();
        if (kt + 3 < nkt)       stage(cur, kt + 3);
        else if (kt == nkt - 3) stage_epi(1, 0);   // gi_r -> buf1
        else if (kt == nkt - 2) stage_epi(2, 1);   // gi_z -> buf2
        else                    stage_epi(0, 2);   // gi_n -> buf0

        __builtin_amdgcn_s_setprio(1);
        #pragma unroll
        for (int mi = 0; mi < 4; ++mi)
            #pragma unroll
            for (int ni = 0; ni < 2; ++ni) {
                ar[mi][ni] = __builtin_amdgcn_mfma_f32_16x16x32_bf16(af[mi], bfr[ni], ar[mi][ni], 0, 0, 0);
                az[mi][ni] = __builtin_amdgcn_mfma_f32_16x16x32_bf16(af[mi], bfz[ni], az[mi][ni], 0, 0, 0);
                ah[mi][ni] = __builtin_amdgcn_mfma_f32_16x16x32_bf16(af[mi], bfn[ni], ah[mi][ni], 0, 0, 0);
            }
        __builtin_amdgcn_s_setprio(0);
        cur = (cur == 2) ? 0 : cur + 1;
    }

    asm volatile("s_waitcnt vmcnt(0)" ::: "memory");
    __builtin_amdgcn_s_barrier();

    // ---- gates: gi_r @10240, gi_z @20480, gi_n @0 (tix128); hv global ----
    unsigned short res[2][4][4];
    #pragma unroll
    for (int ni = 0; ni < 2; ++ni) {
        const int jl = wn * 32 + ni * 16 + fr;
        const int j = j0 + jl;
        const float bhr = b_hh[j], bhz = b_hh[H + j], bhn = b_hh[2 * H + j];
        #pragma unroll
        for (int mi = 0; mi < 4; ++mi) {
            #pragma unroll
            for (int r = 0; r < 4; ++r) {
                const int ml = wm * 64 + mi * 16 + kg * 4 + r;
                const int ix = tix128(ml, jl);
                const float gr = bf2f(smem[10240 + ix]);
                const float gz = bf2f(smem[20480 + ix]);
                const float gn = bf2f(smem[ix]);
                const float hv = bf2f(hbi[(size_t)(m0 + ml) * H + j]);
                const float rg = sigf(ar[mi][ni][r] + gr + bhr);
                const float zg = sigf(az[mi][ni][r] + gz + bhz);
                const float ng = tanhf_fast(gn + rg * (ah[mi][ni][r] + bhn));
                res[ni][mi][r] = f2bf((1.f - zg) * ng + zg * hv);
            }
        }
    }
    __syncthreads();   // gi reads done before res overwrite

    // ---- res -> LDS tile @10240, then coalesced stores ----
    #pragma unroll
    for (int ni = 0; ni < 2; ++ni) {
        const int jl = wn * 32 + ni * 16 + fr;
        #pragma unroll
        for (int mi = 0; mi < 4; ++mi)
            #pragma unroll
            for (int r = 0; r < 4; ++r) {
                const int ml = wm * 64 + mi * 16 + kg * 4 + r;
                smem[10240 + tix128(ml, jl)] = res[ni][mi][r];
            }
    }
    __syncthreads();

    #pragma unroll
    for (int e = 0; e < 4; ++e) {
        const int id = tid + e * 256;         // 1024 chunks of 16B
        const int ml = id >> 3, jw = id & 7;
        const int4 v = *reinterpret_cast<const int4*>(
            &smem[10240 + ((ml >> 4) * 2 + (jw >> 2)) * 512 + (ml & 15) * 32 + (jw & 3) * 8]);
        *reinterpret_cast<int4*>(&hbo[(size_t)(m0 + ml) * H + j0 + jw * 8]) = v;
    }
}

// ---------------------------------------------------------------------------
// Tree level mega-GEMM (unchanged): G = h_c @ [U_iou | U_f]. 64x64 tile,
// 512 blocks, XCD-chunked, 4-deep, stage-early, setprio.
// ---------------------------------------------------------------------------
__global__ __launch_bounds__(256, 4)
void tree_gemm(const unsigned short* __restrict__ hTb,
               const unsigned short* __restrict__ UcombT,  // [2048][512]
               const unsigned short* __restrict__ xgb,     // [N][2048] bf16
               const float* __restrict__ cT,               // [N][512]
               const int* __restrict__ parent,
               int cstart, int pstart,
               float* __restrict__ giou,                   // [PER][1536]
               float* __restrict__ fcs)                    // [PER][512]
{
    constexpr int H = 512, N4H = 2048, G3H = 1536;
    const int nwg = (int)gridDim.x;                        // 512
    const int l = ((int)blockIdx.x & 7) * (nwg >> 3) + ((int)blockIdx.x >> 3);
    const int m0 = (l >> 5) * 64, n0 = (l & 31) * 64;      // col fastest
    const int tid = (int)threadIdx.x, lane = tid & 63, wid = tid >> 6;
    const int wm = wid >> 1, wn = wid & 1;
    const int fr = lane & 15, kg = lane >> 4;
    const int lrow = lane >> 2;
    const int scol = swz(lane & 3, lrow);

    __shared__ unsigned short smem[4 * 4096];

    f32x4 acc[2][2];
    #pragma unroll
    for (int i = 0; i < 2; ++i)
        #pragma unroll
        for (int j = 0; j < 2; ++j)
            acc[i][j] = (f32x4){0.f, 0.f, 0.f, 0.f};

    auto stage = [&](int buf, int kt) {
        const int k0 = kt * 32;
        unsigned short* base = &smem[buf * 4096];
        #pragma unroll
        for (int q = 0; q < 2; ++q) {
            const int c = wid * 2 + q;   // 8 chunks
            const unsigned short* g = (c < 4)
                ? hTb + (size_t)(cstart + m0 + c * 16 + lrow) * H + k0 + scol
                : UcombT + (size_t)(n0 + (c - 4) * 16 + lrow) * H + k0 + scol;
            gload16(g, base + c * 512);
        }
    };

    constexpr int nkt = H / 32;  // 16
    stage(0, 0); stage(1, 1); stage(2, 2); stage(3, 3);
    int cur = 0;

    for (int kt = 0; kt < nkt; ++kt) {
        if (kt + 3 < nkt)      asm volatile("s_waitcnt vmcnt(6)" ::: "memory");
        else if (kt + 2 < nkt) asm volatile("s_waitcnt vmcnt(4)" ::: "memory");
        else if (kt + 1 < nkt) asm volatile("s_waitcnt vmcnt(2)" ::: "memory");
        else                   asm volatile("s_waitcnt vmcnt(0)" ::: "memory");
        __builtin_amdgcn_s_barrier();

        const unsigned short* sb = &smem[cur * 4096];
        bf16x8 af[2], bf[2];
        #pragma unroll
        for (int mi = 0; mi < 2; ++mi) {
            const int row = wm * 32 + mi * 16 + fr;
            af[mi] = *reinterpret_cast<const bf16x8*>(&sb[row * 32 + swz(kg, row)]);
        }
        #pragma unroll
        for (int ni = 0; ni < 2; ++ni) {
            const int row = wn * 32 + ni * 16 + fr;
            bf[ni] = *reinterpret_cast<const bf16x8*>(&sb[2048 + row * 32 + swz(kg, row)]);
        }
        asm volatile("s_waitcnt lgkmcnt(0)" ::: "memory");
        __builtin_amdgcn_s_barrier();
        if (kt + 4 < nkt) stage(cur, kt + 4);

        __builtin_amdgcn_s_setprio(1);
        #pragma unroll
        for (int mi = 0; mi < 2; ++mi)
            #pragma unroll
            for (int ni = 0; ni < 2; ++ni)
                acc[mi][ni] = __builtin_amdgcn_mfma_f32_16x16x32_bf16(
                    af[mi], bf[ni], acc[mi][ni], 0, 0, 0);
        __builtin_amdgcn_s_setprio(0);
        cur = (cur == 3) ? 0 : cur + 1;
    }

    if (n0 < G3H) {
        #pragma unroll
        for (int mi = 0; mi < 2; ++mi)
            #pragma unroll
            for (int r = 0; r < 4; ++r) {
                const int m = m0 + wm * 32 + mi * 16 + kg * 4 + r;
                const int p = parent[cstart + m] - pstart;
                #pragma unroll
                for (int ni = 0; ni < 2; ++ni) {
                    const int n = n0 + wn * 32 + ni * 16 + fr;
                    atomicAdd(&giou[(size_t)p * G3H + n], acc[mi][ni][r]);
                }
            }
    } else {
        #pragma unroll
        for (int mi = 0; mi < 2; ++mi)
            #pragma unroll
            for (int r = 0; r < 4; ++r) {
                const int m = m0 + wm * 32 + mi * 16 + kg * 4 + r;
                const int child = cstart + m;
                const int p = parent[child];
                #pragma unroll
                for (int ni = 0; ni < 2; ++ni) {
                    const int jf = n0 + wn * 32 + ni * 16 + fr - G3H;
                    const float f = sigf(acc[mi][ni][r] +
                                         bf2f(xgb[(size_t)p * N4H + G3H + jf]));
                    atomicAdd(&fcs[(size_t)(p - pstart) * H + jf],
                              f * cT[(size_t)child * H + jf]);
                }
            }
    }
}

// ---------------------------------------------------------------------------
// level update (unchanged); root level writes d_out directly.
// ---------------------------------------------------------------------------
__global__ void level_update(const unsigned short* __restrict__ xgb,
                             float* __restrict__ giou,
                             float* __restrict__ fcs,
                             float* __restrict__ cT, float* __restrict__ hT,
                             unsigned short* __restrict__ hb, int pstart,
                             float* __restrict__ outp, int PH)
{
    constexpr int H = 512, N4H = 2048, G3H = 1536;
    const int idx = blockIdx.x * blockDim.x + threadIdx.x;  // PER*H exact
    const int pi = idx >> 9, j = idx & (H - 1);
    const int p = pstart + pi;
    const size_t xb4 = (size_t)p * N4H;
    const size_t gb = (size_t)pi * G3H;
    const float ig = sigf(bf2f(xgb[xb4 + j]) + giou[gb + j]);
    const float og = sigf(bf2f(xgb[xb4 + H + j]) + giou[gb + H + j]);
    const float ug = tanhf_fast(bf2f(xgb[xb4 + 2 * H + j]) + giou[gb + 2 * H + j]);
    const float cn = ig * ug + fcs[idx];
    const float hn = og * tanhf_fast(cn);
    if (outp) {
        outp[idx] = cn;
        outp[(size_t)PH + idx] = hn;
    } else {
        const size_t off = (size_t)p * H + j;
        cT[off] = cn;
        hT[off] = hn;
        hb[off] = f2bf(hn);
        giou[gb + j] = 0.f;
        giou[gb + H + j] = 0.f;
        giou[gb + 2 * H + j] = 0.f;
        fcs[idx] = 0.f;
    }
}

// ---------------------------------------------------------------------------
extern "C" void kernel_launch(void* const* d_in, const int* in_sizes, int n_in,
                              void* d_out, int out_size, void* d_ws, size_t ws_size,
                              hipStream_t stream)
{
    const float* x_seq = (const float*)d_in[0];
    const float* W_ih  = (const float*)d_in[1];
    const float* W_hh  = (const float*)d_in[2];
    const float* b_ih  = (const float*)d_in[3];
    const float* b_hh  = (const float*)d_in[4];
    const float* Wx    = (const float*)d_in[5];
    const float* bx    = (const float*)d_in[6];
    const float* U_iou = (const float*)d_in[7];
    const float* U_f   = (const float*)d_in[8];
    const int* parent  = (const int*)d_in[9];

    const int threeH = in_sizes[3];          // 1536
    const int H   = threeH / 3;              // 512
    const int I   = in_sizes[1] / threeH;    // 256
    const int N   = in_sizes[9];             // 8192
    const int L   = in_sizes[0] / (N * I);   // 8
    const int PER = in_sizes[11];            // 1024
    const int D   = N / PER;                 // 8

    const size_t NH = (size_t)N * H;
    const size_t PH = (size_t)PER * H;
    const size_t NG = (size_t)N * threeH;    // per-step gi slice elements

    // ---- workspace carve-up ----
    char* p = (char*)d_ws;
    const size_t xb_sz  = (size_t)N * L * I * 2;
    const size_t xgb_sz = (size_t)N * 4 * H * 2;
    const size_t zone_sz = xb_sz > xgb_sz ? xb_sz : xgb_sz;
    unsigned short* xb  = (unsigned short*)p;
    unsigned short* xgb = (unsigned short*)p;    p += zone_sz;
    unsigned short* gi  = (unsigned short*)p;    p += (size_t)N * L * threeH * 2;
    unsigned short* hb0 = (unsigned short*)p;    p += NH * 2;
    unsigned short* hb1 = (unsigned short*)p;    p += NH * 2;
    unsigned short* WihT = (unsigned short*)p;   p += (size_t)threeH * I * 2;
    unsigned short* WhhT = (unsigned short*)p;   p += (size_t)threeH * H * 2;
    unsigned short* WxT  = (unsigned short*)p;   p += (size_t)4 * H * H * 2;
    unsigned short* UcombT = (unsigned short*)p; p += (size_t)4 * H * H * 2;
    if ((size_t)(p - (char*)d_ws) > ws_size) return;
    // tree-phase aliases inside gi region (gi dead post-GRU):
    float* cT   = (float*)gi;
    float* hT   = cT + NH;
    float* giou = hT + NH;
    float* fcs  = giou + PH * 3;

    // ---- prep ----
    {
        const int n = N * L * I;
        cvt_f32_bf16<<<(n / 4 + 255) / 256, 256, 0, stream>>>(x_seq, xb, n);
        dim3 blk(32, 8);
        transpose_cvt<<<dim3(threeH / 32, I / 32), blk, 0, stream>>>(W_ih, WihT, I, threeH);
        transpose_cvt<<<dim3(threeH / 32, H / 32), blk, 0, stream>>>(W_hh, WhhT, H, threeH);
        transpose_cvt<<<dim3(4 * H / 32, H / 32), blk, 0, stream>>>(Wx, WxT, H, 4 * H);
        transpose_cvt<<<dim3(threeH / 32, H / 32), blk, 0, stream>>>(U_iou, UcombT, H, threeH);
        transpose_cvt<<<dim3(H / 32, H / 32), blk, 0, stream>>>(
            U_f, UcombT + (size_t)threeH * H, H, H);
    }

    // ---- Phase 0: gi[t][m] = x[m][t]@Wih + b_ih (one big GEMM) ----
    gemm_bf16out<<<(N * L / 128) * (threeH / 128), 256, 0, stream>>>(
        xb, WihT, b_ih, gi, N * L, threeH, I, threeH / 128,
        N, L * I, I);

    // ---- Phase 1: GRU recurrence. Step 0 is pointwise (h=0). ----
    gru_step0<<<(int)(NH / 8 / 256), 256, 0, stream>>>(gi, hb1, b_hh);
    {
        dim3 grid(N / 128, H / 64);
        for (int t = 1; t < L; ++t) {
            const unsigned short* hin = (t & 1) ? hb1 : hb0;
            unsigned short* hout = (t & 1) ? hb0 : hb1;
            gru_step<<<grid, 256, 0, stream>>>(gi + (size_t)t * NG, hin, hout,
                                               WhhT, b_hh);
        }
        // L even -> enc bf16 in hb0
    }

    // ---- Phase 2: xg(bf16) = enc @ Wx + bx ----
    gemm_bf16out<<<(N / 128) * (4 * H / 128), 256, 0, stream>>>(
        hb0, WxT, bx, xgb, N, 4 * H, H, 4 * H / 128,
        N, H, 0);

    // ---- Phase 3: tree levels (gi dead; cT/hT/giou/fcs alias it) ----
    hipMemsetAsync(giou, 0, PH * 4 * 4, stream);   // giou + fcs (contiguous)
    unsigned short* hTb = hb1;
    const int pw_blocks = (int)(PH / 256);

    for (int lvl = D - 1; lvl >= 0; --lvl) {
        const int pstart = lvl * PER;
        const int cstart = (lvl + 1) * PER;

        if (lvl < D - 1)
            tree_gemm<<<(PER / 64) * (4 * H / 64), 256, 0, stream>>>(
                hTb, UcombT, xgb, cT, parent, cstart, pstart, giou, fcs);

        level_update<<<pw_blocks, 256, 0, stream>>>(
            xgb, giou, fcs, cT, hT, hTb, pstart,
            (lvl == 0) ? (float*)d_out : nullptr, (int)PH);
    }
}

// Round 20
// 450.245 us; speedup vs baseline: 2.2650x; 1.0229x over previous
//
#include <hip/hip_runtime.h>
#include <math.h>

typedef short bf16x8 __attribute__((ext_vector_type(8)));
typedef float f32x4 __attribute__((ext_vector_type(4)));

__device__ __forceinline__ float sigf(float x) {
    return __builtin_amdgcn_rcpf(1.f + __expf(-x));
}
__device__ __forceinline__ float tanhf_fast(float x) {
    const float e = __expf(2.f * x);
    return 1.f - 2.f * __builtin_amdgcn_rcpf(e + 1.f);
}

__device__ __forceinline__ unsigned short f2bf(float f) {
    union { float f; unsigned u; } v; v.f = f;
    unsigned r = (v.u + 0x7FFFu + ((v.u >> 16) & 1u)) >> 16;
    return (unsigned short)r;
}
__device__ __forceinline__ float bf2f(unsigned short u) {
    union { unsigned u; float f; } v; v.u = ((unsigned)u) << 16; return v.f;
}

// async global->LDS, 16B per lane; LDS dest = wave-uniform base + lane*16B.
__device__ __forceinline__ void gload16(const unsigned short* g, unsigned short* l) {
    __builtin_amdgcn_global_load_lds(
        (const __attribute__((address_space(1))) void*)g,
        (__attribute__((address_space(3))) void*)l, 16, 0, 0);
}

// Chunk = 16 rows x 32 ushorts (1 KiB). Lane i -> (row=i>>2, slot=i&3).
// Both-sides bank swizzle for K-tiles: source col = (slot ^ ((row>>1)&3))*8.
__device__ __forceinline__ int swz(int slot, int row) {
    return (slot ^ ((row >> 1) & 3)) * 8;
}
// Unswizzled chunked-tile index (16-row chunks, 2 col-halves of 32).
__device__ __forceinline__ int tix128(int ml, int jl) {
    return ((ml >> 4) * 2 + (jl >> 5)) * 512 + (ml & 15) * 32 + (jl & 31);
}

// ---------------------------------------------------------------------------
// prep kernels
// ---------------------------------------------------------------------------
__global__ void cvt_f32_bf16(const float* __restrict__ src,
                             unsigned short* __restrict__ dst, int n)
{
    const int i = (blockIdx.x * blockDim.x + threadIdx.x) * 4;
    if (i >= n) return;
    const float4 v = *reinterpret_cast<const float4*>(src + i);
    ushort4 o;
    o.x = f2bf(v.x); o.y = f2bf(v.y); o.z = f2bf(v.z); o.w = f2bf(v.w);
    *reinterpret_cast<ushort4*>(dst + i) = o;
}

// all 5 weight transposes in one launch (tile jobs decoded from blockIdx)
__global__ void transpose_all(const float* __restrict__ W_ih,
                              const float* __restrict__ W_hh,
                              const float* __restrict__ Wx,
                              const float* __restrict__ U_iou,
                              const float* __restrict__ U_f,
                              unsigned short* __restrict__ WihT,
                              unsigned short* __restrict__ WhhT,
                              unsigned short* __restrict__ WxT,
                              unsigned short* __restrict__ UcombT,
                              int threeH, int I, int H,
                              int n1, int n2, int n3, int n4)
{
    int b = (int)blockIdx.x;
    const float* src; unsigned short* dst; int rows, cols;
    if (b < n1)      { src = W_ih;  dst = WihT;   rows = I; cols = threeH; }
    else if (b < n2) { src = W_hh;  dst = WhhT;   rows = H; cols = threeH; b -= n1; }
    else if (b < n3) { src = Wx;    dst = WxT;    rows = H; cols = 4 * H;  b -= n2; }
    else if (b < n4) { src = U_iou; dst = UcombT; rows = H; cols = threeH; b -= n3; }
    else { src = U_f; dst = UcombT + (size_t)threeH * H; rows = H; cols = H; b -= n4; }
    const int ncx = cols / 32;
    const int bc = (b % ncx) * 32, br = (b / ncx) * 32;
    __shared__ float tile[32][33];
    const int tx = threadIdx.x, ty = threadIdx.y;  // block (32,8)
    #pragma unroll
    for (int i = 0; i < 32; i += 8)
        tile[ty + i][tx] = src[(size_t)(br + ty + i) * cols + bc + tx];
    __syncthreads();
    #pragma unroll
    for (int i = 0; i < 32; i += 8)
        dst[(size_t)(bc + ty + i) * rows + br + tx] = f2bf(tile[tx][ty + i]);
}

// ---------------------------------------------------------------------------
// bf16-output GEMM: Cb = A' @ BT^T + bias, row-gather A'.
// 1-D grid, XCD-CHUNKED remap. 128x128, 3-deep, stage-early, setprio.
// ---------------------------------------------------------------------------
__global__ __launch_bounds__(256)
void gemm_bf16out(const unsigned short* __restrict__ A,
                  const unsigned short* __restrict__ BT,
                  const float* __restrict__ bias,
                  unsigned short* __restrict__ Cb, int M, int N, int K,
                  int ncols, int Mrows, int rstride, int tstride)
{
    const int nwg = (int)gridDim.x;
    const int l = ((int)blockIdx.x & 7) * (nwg >> 3) + ((int)blockIdx.x >> 3);
    const int m0 = (l / ncols) * 128, n0 = (l % ncols) * 128;
    const size_t abase = (size_t)(m0 % Mrows) * rstride
                       + (size_t)(m0 / Mrows) * tstride;
    const int tid = (int)threadIdx.x, lane = tid & 63, wid = tid >> 6;
    const int wm = wid >> 1, wn = wid & 1;
    const int fr = lane & 15, kg = lane >> 4;
    const int lrow = lane >> 2;
    const int scol = swz(lane & 3, lrow);

    __shared__ unsigned short smem[3 * 8192];

    f32x4 acc[4][4];
    #pragma unroll
    for (int i = 0; i < 4; ++i)
        #pragma unroll
        for (int j = 0; j < 4; ++j)
            acc[i][j] = (f32x4){0.f, 0.f, 0.f, 0.f};

    auto stage = [&](int buf, int kt) {
        const int k0 = kt * 32;
        unsigned short* base = &smem[buf * 8192];
        #pragma unroll
        for (int q = 0; q < 4; ++q) {
            const int c = wid * 4 + q;
            const unsigned short* g = (c < 8)
                ? A + abase + (size_t)(c * 16 + lrow) * rstride + k0 + scol
                : BT + (size_t)(n0 + (c - 8) * 16 + lrow) * K + k0 + scol;
            gload16(g, base + c * 512);
        }
    };

    const int nkt = K >> 5;
    stage(0, 0); stage(1, 1); stage(2, 2);
    int cur = 0;

    for (int kt = 0; kt < nkt; ++kt) {
        if (kt + 2 < nkt)      asm volatile("s_waitcnt vmcnt(8)" ::: "memory");
        else if (kt + 1 < nkt) asm volatile("s_waitcnt vmcnt(4)" ::: "memory");
        else                   asm volatile("s_waitcnt vmcnt(0)" ::: "memory");
        __builtin_amdgcn_s_barrier();

        const unsigned short* sb = &smem[cur * 8192];
        bf16x8 af[4], bf[4];
        #pragma unroll
        for (int mi = 0; mi < 4; ++mi) {
            const int row = wm * 64 + mi * 16 + fr;
            af[mi] = *reinterpret_cast<const bf16x8*>(&sb[row * 32 + swz(kg, row)]);
        }
        #pragma unroll
        for (int ni = 0; ni < 4; ++ni) {
            const int row = wn * 64 + ni * 16 + fr;
            bf[ni] = *reinterpret_cast<const bf16x8*>(&sb[4096 + row * 32 + swz(kg, row)]);
        }
        asm volatile("s_waitcnt lgkmcnt(0)" ::: "memory");
        __builtin_amdgcn_s_barrier();
        if (kt + 3 < nkt) stage(cur, kt + 3);

        __builtin_amdgcn_s_setprio(1);
        #pragma unroll
        for (int mi = 0; mi < 4; ++mi)
            #pragma unroll
            for (int ni = 0; ni < 4; ++ni)
                acc[mi][ni] = __builtin_amdgcn_mfma_f32_16x16x32_bf16(
                    af[mi], bf[ni], acc[mi][ni], 0, 0, 0);
        __builtin_amdgcn_s_setprio(0);
        cur = (cur == 2) ? 0 : cur + 1;
    }

    #pragma unroll
    for (int ni = 0; ni < 4; ++ni) {
        const int nl = wn * 64 + ni * 16 + fr;
        const float bv = bias[n0 + nl];
        #pragma unroll
        for (int mi = 0; mi < 4; ++mi)
            #pragma unroll
            for (int r = 0; r < 4; ++r) {
                const int ml = wm * 64 + mi * 16 + kg * 4 + r;
                smem[ml * 132 + nl] = f2bf(acc[mi][ni][r] + bv);
            }
    }
    __syncthreads();
    #pragma unroll
    for (int e = 0; e < 8; ++e) {
        const int id = tid + e * 256;          // 2048 chunks of 16B
        const int row = id >> 4, cw = id & 15;
        const int4 v = *reinterpret_cast<const int4*>(&smem[row * 132 + cw * 8]);
        *reinterpret_cast<int4*>(&Cb[(size_t)(m0 + row) * N + n0 + cw * 8]) = v;
    }
}

// ---------------------------------------------------------------------------
// GRU step 0 (h=0): pure pointwise from gi (t-major; t=0 slice is first).
// ---------------------------------------------------------------------------
__global__ void gru_step0(const unsigned short* __restrict__ gi,  // [L][N][1536]
                          unsigned short* __restrict__ hbo,
                          const float* __restrict__ b_hh)
{
    constexpr int H = 512, G3H = 1536;
    const int idx = blockIdx.x * blockDim.x + threadIdx.x;  // N*H/8 exact
    const int m = idx >> 6, jv = idx & 63;
    const size_t gb = (size_t)m * G3H + jv * 8;
    const bf16x8 gr8 = *reinterpret_cast<const bf16x8*>(gi + gb);
    const bf16x8 gz8 = *reinterpret_cast<const bf16x8*>(gi + gb + H);
    const bf16x8 gn8 = *reinterpret_cast<const bf16x8*>(gi + gb + 2 * H);
    bf16x8 o;
    #pragma unroll
    for (int k = 0; k < 8; ++k) {
        const int j = jv * 8 + k;
        const float r = sigf(bf2f((unsigned short)gr8[k]) + b_hh[j]);
        const float z = sigf(bf2f((unsigned short)gz8[k]) + b_hh[H + j]);
        const float n = tanhf_fast(bf2f((unsigned short)gn8[k]) + r * b_hh[2 * H + j]);
        o[k] = (short)f2bf((1.f - z) * n);
    }
    *reinterpret_cast<bf16x8*>(hbo + (size_t)m * H + jv * 8) = o;
}

// ---------------------------------------------------------------------------
// GRU step (recurrent part): acc = h @ W_hh; epilogue combines with gi and h.
// Tile 128(m) x 64(j); grid (64,8) = 512 blocks = exactly 2/CU.
// LDS 64 KiB: 3 x 20 KiB buffers. 3-deep, uniform vmcnt(10/9/8) ladder;
// epilogue gi tiles prefetched into freed buffers; hv direct from global.
// ---------------------------------------------------------------------------
__global__ __launch_bounds__(256, 2)
void gru_step(const unsigned short* __restrict__ giT,  // t's slice [N][1536]
              const unsigned short* __restrict__ hbi,
              unsigned short* __restrict__ hbo,
              const unsigned short* __restrict__ WhhT, // [1536][512]
              const float* __restrict__ b_hh)
{
    constexpr int H = 512, G3H = 1536;
    const int m0 = blockIdx.x * 128, j0 = blockIdx.y * 64;
    const int tid = (int)threadIdx.x, lane = tid & 63, wid = tid >> 6;
    const int wm = wid >> 1, wn = wid & 1;
    const int fr = lane & 15, kg = lane >> 4;
    const int lrow = lane >> 2;
    const int scol = swz(lane & 3, lrow);
    const int ucol = (lane & 3) * 8;

    __shared__ unsigned short smem[3 * 10240 + 2048];   // 64 KiB

    f32x4 ar[4][2], az[4][2], ah[4][2];
    #pragma unroll
    for (int i = 0; i < 4; ++i)
        #pragma unroll
        for (int j = 0; j < 2; ++j) {
            ar[i][j] = (f32x4){0.f, 0.f, 0.f, 0.f};
            az[i][j] = (f32x4){0.f, 0.f, 0.f, 0.f};
            ah[i][j] = (f32x4){0.f, 0.f, 0.f, 0.f};
        }

    constexpr int nkt = H / 32;   // 16

    auto stage = [&](int buf, int kt) {
        const int k0 = kt * 32;
        unsigned short* base = &smem[buf * 10240];
        #pragma unroll
        for (int q = 0; q < 5; ++q) {
            const int c = wid * 5 + q;
            if (c < 8) {
                const unsigned short* g =
                    hbi + (size_t)(m0 + c * 16 + lrow) * H + k0 + scol;
                gload16(g, base + c * 512);
            } else {
                const int bc = c - 8, gate = bc >> 2, rowg = bc & 3;
                const unsigned short* g =
                    WhhT + (size_t)(gate * H + j0 + rowg * 16 + lrow) * H + k0 + scol;
                gload16(g, base + c * 512);
            }
        }
    };
    auto stage_epi = [&](int buf, int g) {
        unsigned short* base = &smem[buf * 10240];
        #pragma unroll
        for (int q = 0; q < 4; ++q) {
            const int c = wid * 4 + q;            // 16 chunks
            const int rowg = c >> 1, colg = c & 1;
            const unsigned short* src =
                giT + (size_t)(m0 + rowg * 16 + lrow) * G3H
                    + g * H + j0 + colg * 32 + ucol;
            gload16(src, base + c * 512);
        }
    };

    stage(0, 0); stage(1, 1); stage(2, 2);
    int cur = 0;

    for (int kt = 0; kt < nkt; ++kt) {
        if (kt <= nkt - 3)      asm volatile("s_waitcnt vmcnt(10)" ::: "memory");
        else if (kt == nkt - 2) asm volatile("s_waitcnt vmcnt(9)" ::: "memory");
        else                    asm volatile("s_waitcnt vmcnt(8)" ::: "memory");
        __builtin_amdgcn_s_barrier();

        const unsigned short* sb = &smem[cur * 10240];
        bf16x8 af[4], bfr[2], bfz[2], bfn[2];
        #pragma unroll
        for (int mi = 0; mi < 4; ++mi) {
            const int row = wm * 64 + mi * 16 + fr;
            af[mi] = *reinterpret_cast<const bf16x8*>(&sb[row * 32 + swz(kg, row)]);
        }
        #pragma unroll
        for (int ni = 0; ni < 2; ++ni) {
            const int row = wn * 32 + ni * 16 + fr;
            const int sw = swz(kg, row);
            bfr[ni] = *reinterpret_cast<const bf16x8*>(&sb[4096 + (row) * 32 + sw]);
            bfz[ni] = *reinterpret_cast<const bf16x8*>(&sb[4096 + (64 + row) * 32 + sw]);
            bfn[ni] = *reinterpret_cast<const bf16x8*>(&sb[4096 + (128 + row) * 32 + sw]);
        }
        asm volatile("s_waitcnt lgkmcnt(0)" ::: "memory");
        __builtin_amdgcn_s_barrier();
        if (kt + 3 < nkt)       stage(cur, kt + 3);
        else if (kt == nkt - 3) stage_epi(1, 0);   // gi_r -> buf1
        else if (kt == nkt - 2) stage_epi(2, 1);   // gi_z -> buf2
        else                    stage_epi(0, 2);   // gi_n -> buf0

        __builtin_amdgcn_s_setprio(1);
        #pragma unroll
        for (int mi = 0; mi < 4; ++mi)
            #pragma unroll
            for (int ni = 0; ni < 2; ++ni) {
                ar[mi][ni] = __builtin_amdgcn_mfma_f32_16x16x32_bf16(af[mi], bfr[ni], ar[mi][ni], 0, 0, 0);
                az[mi][ni] = __builtin_amdgcn_mfma_f32_16x16x32_bf16(af[mi], bfz[ni], az[mi][ni], 0, 0, 0);
                ah[mi][ni] = __builtin_amdgcn_mfma_f32_16x16x32_bf16(af[mi], bfn[ni], ah[mi][ni], 0, 0, 0);
            }
        __builtin_amdgcn_s_setprio(0);
        cur = (cur == 2) ? 0 : cur + 1;
    }

    asm volatile("s_waitcnt vmcnt(0)" ::: "memory");
    __builtin_amdgcn_s_barrier();

    // ---- gates: gi_r @10240, gi_z @20480, gi_n @0 (tix128); hv global ----
    unsigned short res[2][4][4];
    #pragma unroll
    for (int ni = 0; ni < 2; ++ni) {
        const int jl = wn * 32 + ni * 16 + fr;
        const int j = j0 + jl;
        const float bhr = b_hh[j], bhz = b_hh[H + j], bhn = b_hh[2 * H + j];
        #pragma unroll
        for (int mi = 0; mi < 4; ++mi) {
            #pragma unroll
            for (int r = 0; r < 4; ++r) {
                const int ml = wm * 64 + mi * 16 + kg * 4 + r;
                const int ix = tix128(ml, jl);
                const float gr = bf2f(smem[10240 + ix]);
                const float gz = bf2f(smem[20480 + ix]);
                const float gn = bf2f(smem[ix]);
                const float hv = bf2f(hbi[(size_t)(m0 + ml) * H + j]);
                const float rg = sigf(ar[mi][ni][r] + gr + bhr);
                const float zg = sigf(az[mi][ni][r] + gz + bhz);
                const float ng = tanhf_fast(gn + rg * (ah[mi][ni][r] + bhn));
                res[ni][mi][r] = f2bf((1.f - zg) * ng + zg * hv);
            }
        }
    }
    __syncthreads();   // gi reads done before res overwrite

    #pragma unroll
    for (int ni = 0; ni < 2; ++ni) {
        const int jl = wn * 32 + ni * 16 + fr;
        #pragma unroll
        for (int mi = 0; mi < 4; ++mi)
            #pragma unroll
            for (int r = 0; r < 4; ++r) {
                const int ml = wm * 64 + mi * 16 + kg * 4 + r;
                smem[10240 + tix128(ml, jl)] = res[ni][mi][r];
            }
    }
    __syncthreads();

    #pragma unroll
    for (int e = 0; e < 4; ++e) {
        const int id = tid + e * 256;         // 1024 chunks of 16B
        const int ml = id >> 3, jw = id & 7;
        const int4 v = *reinterpret_cast<const int4*>(
            &smem[10240 + ((ml >> 4) * 2 + (jw >> 2)) * 512 + (ml & 15) * 32 + (jw & 3) * 8]);
        *reinterpret_cast<int4*>(&hbo[(size_t)(m0 + ml) * H + j0 + jw * 8]) = v;
    }
}

// ---------------------------------------------------------------------------
// Tree level mega-GEMM: G = h_c @ [U_iou | U_f]. 64x64 tile, 512 blocks,
// XCD-chunked. 4-deep pipeline, stage-early, setprio.
// ---------------------------------------------------------------------------
__global__ __launch_bounds__(256, 4)
void tree_gemm(const unsigned short* __restrict__ hTb,
               const unsigned short* __restrict__ UcombT,  // [2048][512]
               const unsigned short* __restrict__ xgb,     // [N][2048] bf16
               const float* __restrict__ cT,               // [N][512]
               const int* __restrict__ parent,
               int cstart, int pstart,
               float* __restrict__ giou,                   // [PER][1536]
               float* __restrict__ fcs)                    // [PER][512]
{
    constexpr int H = 512, N4H = 2048, G3H = 1536;
    const int nwg = (int)gridDim.x;                        // 512
    const int l = ((int)blockIdx.x & 7) * (nwg >> 3) + ((int)blockIdx.x >> 3);
    const int m0 = (l >> 5) * 64, n0 = (l & 31) * 64;      // col fastest
    const int tid = (int)threadIdx.x, lane = tid & 63, wid = tid >> 6;
    const int wm = wid >> 1, wn = wid & 1;
    const int fr = lane & 15, kg = lane >> 4;
    const int lrow = lane >> 2;
    const int scol = swz(lane & 3, lrow);

    __shared__ unsigned short smem[4 * 4096];

    f32x4 acc[2][2];
    #pragma unroll
    for (int i = 0; i < 2; ++i)
        #pragma unroll
        for (int j = 0; j < 2; ++j)
            acc[i][j] = (f32x4){0.f, 0.f, 0.f, 0.f};

    auto stage = [&](int buf, int kt) {
        const int k0 = kt * 32;
        unsigned short* base = &smem[buf * 4096];
        #pragma unroll
        for (int q = 0; q < 2; ++q) {
            const int c = wid * 2 + q;   // 8 chunks
            const unsigned short* g = (c < 4)
                ? hTb + (size_t)(cstart + m0 + c * 16 + lrow) * H + k0 + scol
                : UcombT + (size_t)(n0 + (c - 4) * 16 + lrow) * H + k0 + scol;
            gload16(g, base + c * 512);
        }
    };

    constexpr int nkt = H / 32;  // 16
    stage(0, 0); stage(1, 1); stage(2, 2); stage(3, 3);
    int cur = 0;

    for (int kt = 0; kt < nkt; ++kt) {
        if (kt + 3 < nkt)      asm volatile("s_waitcnt vmcnt(6)" ::: "memory");
        else if (kt + 2 < nkt) asm volatile("s_waitcnt vmcnt(4)" ::: "memory");
        else if (kt + 1 < nkt) asm volatile("s_waitcnt vmcnt(2)" ::: "memory");
        else                   asm volatile("s_waitcnt vmcnt(0)" ::: "memory");
        __builtin_amdgcn_s_barrier();

        const unsigned short* sb = &smem[cur * 4096];
        bf16x8 af[2], bf[2];
        #pragma unroll
        for (int mi = 0; mi < 2; ++mi) {
            const int row = wm * 32 + mi * 16 + fr;
            af[mi] = *reinterpret_cast<const bf16x8*>(&sb[row * 32 + swz(kg, row)]);
        }
        #pragma unroll
        for (int ni = 0; ni < 2; ++ni) {
            const int row = wn * 32 + ni * 16 + fr;
            bf[ni] = *reinterpret_cast<const bf16x8*>(&sb[2048 + row * 32 + swz(kg, row)]);
        }
        asm volatile("s_waitcnt lgkmcnt(0)" ::: "memory");
        __builtin_amdgcn_s_barrier();
        if (kt + 4 < nkt) stage(cur, kt + 4);

        __builtin_amdgcn_s_setprio(1);
        #pragma unroll
        for (int mi = 0; mi < 2; ++mi)
            #pragma unroll
            for (int ni = 0; ni < 2; ++ni)
                acc[mi][ni] = __builtin_amdgcn_mfma_f32_16x16x32_bf16(
                    af[mi], bf[ni], acc[mi][ni], 0, 0, 0);
        __builtin_amdgcn_s_setprio(0);
        cur = (cur == 3) ? 0 : cur + 1;
    }

    if (n0 < G3H) {
        #pragma unroll
        for (int mi = 0; mi < 2; ++mi)
            #pragma unroll
            for (int r = 0; r < 4; ++r) {
                const int m = m0 + wm * 32 + mi * 16 + kg * 4 + r;
                const int p = parent[cstart + m] - pstart;
                #pragma unroll
                for (int ni = 0; ni < 2; ++ni) {
                    const int n = n0 + wn * 32 + ni * 16 + fr;
                    atomicAdd(&giou[(size_t)p * G3H + n], acc[mi][ni][r]);
                }
            }
    } else {
        #pragma unroll
        for (int mi = 0; mi < 2; ++mi)
            #pragma unroll
            for (int r = 0; r < 4; ++r) {
                const int m = m0 + wm * 32 + mi * 16 + kg * 4 + r;
                const int child = cstart + m;
                const int p = parent[child];
                #pragma unroll
                for (int ni = 0; ni < 2; ++ni) {
                    const int jf = n0 + wn * 32 + ni * 16 + fr - G3H;
                    const float f = sigf(acc[mi][ni][r] +
                                         bf2f(xgb[(size_t)p * N4H + G3H + jf]));
                    atomicAdd(&fcs[(size_t)(p - pstart) * H + jf],
                              f * cT[(size_t)child * H + jf]);
                }
            }
    }
}

// ---------------------------------------------------------------------------
// level update. prime==1 (deepest level): treat giou/fcs as zero (no reads).
// Always leaves giou/fcs slots zeroed (invariant across graph replays, no
// memset needed). Root level (outp) writes the kernel output directly.
// ---------------------------------------------------------------------------
__global__ void level_update(const unsigned short* __restrict__ xgb,
                             float* __restrict__ giou,
                             float* __restrict__ fcs,
                             float* __restrict__ cT, float* __restrict__ hT,
                             unsigned short* __restrict__ hb, int pstart,
                             float* __restrict__ outp, int PH, int prime)
{
    constexpr int H = 512, N4H = 2048, G3H = 1536;
    const int idx = blockIdx.x * blockDim.x + threadIdx.x;  // PER*H exact
    const int pi = idx >> 9, j = idx & (H - 1);
    const int p = pstart + pi;
    const size_t xb4 = (size_t)p * N4H;
    const size_t gb = (size_t)pi * G3H;
    float gv0 = 0.f, gv1 = 0.f, gv2 = 0.f, fv = 0.f;
    if (!prime) {
        gv0 = giou[gb + j]; gv1 = giou[gb + H + j];
        gv2 = giou[gb + 2 * H + j]; fv = fcs[idx];
    }
    const float ig = sigf(bf2f(xgb[xb4 + j]) + gv0);
    const float og = sigf(bf2f(xgb[xb4 + H + j]) + gv1);
    const float ug = tanhf_fast(bf2f(xgb[xb4 + 2 * H + j]) + gv2);
    const float cn = ig * ug + fv;
    const float hn = og * tanhf_fast(cn);
    if (outp) {
        outp[idx] = cn;
        outp[(size_t)PH + idx] = hn;
    } else {
        const size_t off = (size_t)p * H + j;
        cT[off] = cn;
        hT[off] = hn;
        hb[off] = f2bf(hn);
    }
    giou[gb + j] = 0.f;
    giou[gb + H + j] = 0.f;
    giou[gb + 2 * H + j] = 0.f;
    fcs[idx] = 0.f;
}

// ---------------------------------------------------------------------------
extern "C" void kernel_launch(void* const* d_in, const int* in_sizes, int n_in,
                              void* d_out, int out_size, void* d_ws, size_t ws_size,
                              hipStream_t stream)
{
    const float* x_seq = (const float*)d_in[0];
    const float* W_ih  = (const float*)d_in[1];
    const float* W_hh  = (const float*)d_in[2];
    const float* b_ih  = (const float*)d_in[3];
    const float* b_hh  = (const float*)d_in[4];
    const float* Wx    = (const float*)d_in[5];
    const float* bx    = (const float*)d_in[6];
    const float* U_iou = (const float*)d_in[7];
    const float* U_f   = (const float*)d_in[8];
    const int* parent  = (const int*)d_in[9];

    const int threeH = in_sizes[3];          // 1536
    const int H   = threeH / 3;              // 512
    const int I   = in_sizes[1] / threeH;    // 256
    const int N   = in_sizes[9];             // 8192
    const int L   = in_sizes[0] / (N * I);   // 8
    const int PER = in_sizes[11];            // 1024
    const int D   = N / PER;                 // 8

    const size_t NH = (size_t)N * H;
    const size_t PH = (size_t)PER * H;
    const size_t NG = (size_t)N * threeH;    // per-step gi slice elements

    // ---- workspace carve-up ----
    char* p = (char*)d_ws;
    const size_t xb_sz  = (size_t)N * L * I * 2;
    const size_t xgb_sz = (size_t)N * 4 * H * 2;
    const size_t zone_sz = xb_sz > xgb_sz ? xb_sz : xgb_sz;
    unsigned short* xb  = (unsigned short*)p;
    unsigned short* xgb = (unsigned short*)p;    p += zone_sz;
    unsigned short* gi  = (unsigned short*)p;    p += (size_t)N * L * threeH * 2;
    unsigned short* hb0 = (unsigned short*)p;    p += NH * 2;
    unsigned short* hb1 = (unsigned short*)p;    p += NH * 2;
    unsigned short* WihT = (unsigned short*)p;   p += (size_t)threeH * I * 2;
    unsigned short* WhhT = (unsigned short*)p;   p += (size_t)threeH * H * 2;
    unsigned short* WxT  = (unsigned short*)p;   p += (size_t)4 * H * H * 2;
    unsigned short* UcombT = (unsigned short*)p; p += (size_t)4 * H * H * 2;
    if ((size_t)(p - (char*)d_ws) > ws_size) return;
    // tree-phase aliases inside gi region (gi dead post-GRU):
    float* cT   = (float*)gi;
    float* hT   = cT + NH;
    float* giou = hT + NH;
    float* fcs  = giou + PH * 3;

    // ---- prep (2 launches) ----
    {
        const int n = N * L * I;
        cvt_f32_bf16<<<(n / 4 + 255) / 256, 256, 0, stream>>>(x_seq, xb, n);
        const int n1 = (threeH / 32) * (I / 32);
        const int n2 = n1 + (threeH / 32) * (H / 32);
        const int n3 = n2 + (4 * H / 32) * (H / 32);
        const int n4 = n3 + (threeH / 32) * (H / 32);
        const int n5 = n4 + (H / 32) * (H / 32);
        transpose_all<<<n5, dim3(32, 8), 0, stream>>>(
            W_ih, W_hh, Wx, U_iou, U_f, WihT, WhhT, WxT, UcombT,
            threeH, I, H, n1, n2, n3, n4);
    }

    // ---- Phase 0: gi[t][m] = x[m][t]@Wih + b_ih (one big GEMM) ----
    gemm_bf16out<<<(N * L / 128) * (threeH / 128), 256, 0, stream>>>(
        xb, WihT, b_ih, gi, N * L, threeH, I, threeH / 128,
        N, L * I, I);

    // ---- Phase 1: GRU recurrence. Step 0 is pointwise (h=0). ----
    gru_step0<<<(int)(NH / 8 / 256), 256, 0, stream>>>(gi, hb1, b_hh);
    {
        dim3 grid(N / 128, H / 64);
        for (int t = 1; t < L; ++t) {
            const unsigned short* hin = (t & 1) ? hb1 : hb0;
            unsigned short* hout = (t & 1) ? hb0 : hb1;
            gru_step<<<grid, 256, 0, stream>>>(gi + (size_t)t * NG, hin, hout,
                                               WhhT, b_hh);
        }
        // L even -> enc bf16 in hb0
    }

    // ---- Phase 2: xg(bf16) = enc @ Wx + bx ----
    gemm_bf16out<<<(N / 128) * (4 * H / 128), 256, 0, stream>>>(
        hb0, WxT, bx, xgb, N, 4 * H, H, 4 * H / 128,
        N, H, 0);

    // ---- Phase 3: tree levels (gi dead; cT/hT/giou/fcs alias it).
    //      lvl=D-1 update primes zeros -> no memset; every update re-zeros
    //      its slots so the invariant holds across graph replays. ----
    unsigned short* hTb = hb1;
    const int pw_blocks = (int)(PH / 256);

    for (int lvl = D - 1; lvl >= 0; --lvl) {
        const int pstart = lvl * PER;
        const int cstart = (lvl + 1) * PER;

        if (lvl < D - 1)
            tree_gemm<<<(PER / 64) * (4 * H / 64), 256, 0, stream>>>(
                hTb, UcombT, xgb, cT, parent, cstart, pstart, giou, fcs);

        level_update<<<pw_blocks, 256, 0, stream>>>(
            xgb, giou, fcs, cT, hT, hTb, pstart,
            (lvl == 0) ? (float*)d_out : nullptr, (int)PH,
            (lvl == D - 1) ? 1 : 0);
    }
}